// Round 6
// baseline (28409.253 us; speedup 1.0000x reference)
//
#include <hip/hip_runtime.h>
#include <stdint.h>

#define NEG_INF -100000000.0f

typedef unsigned short u16;
typedef unsigned long long u64;
typedef __attribute__((ext_vector_type(8))) short v8s;
typedef __attribute__((ext_vector_type(4))) short v4s;
typedef __attribute__((ext_vector_type(4))) float v4f;

__device__ __forceinline__ float bf2f(u16 h){ return __uint_as_float(((unsigned)h)<<16); }
__device__ __forceinline__ u16 f2bf(float f){
  unsigned u = __float_as_uint(f);
  u = u + 0x7fffu + ((u>>16)&1u);
  return (u16)(u>>16);
}
__device__ __forceinline__ float sigm(float x){ return 1.0f/(1.0f+__expf(-x)); }
__device__ __forceinline__ float ftanh(float x){
  x = fminf(15.0f, fmaxf(-15.0f, x));
  float e = __expf(2.0f*x);
  return (e-1.0f)/(e+1.0f);
}

// write-through (coherence-point) 16B h store; consumer loads are PLAIN
__device__ __forceinline__ void store_h16(u16* p, u64 a, u64 b){
  __hip_atomic_store((u64*)p,     a, __ATOMIC_RELAXED, __HIP_MEMORY_SCOPE_AGENT);
  __hip_atomic_store((u64*)(p+4), b, __ATOMIC_RELAXED, __HIP_MEMORY_SCOPE_AGENT);
}

// ---------------------------------------------------------------------------
// Fused f32 -> bf16 arena conversion
// ---------------------------------------------------------------------------
struct CvtTab {
  const float* src[31];
  unsigned off[31];
  unsigned n[31];
  unsigned total;
};

__global__ __launch_bounds__(256) void cvt_all(CvtTab tab, u16* __restrict__ arena){
  unsigned e0 = (blockIdx.x*256u + threadIdx.x)*8u;
  if (e0 >= tab.total) return;
  int s = 0;
#pragma unroll 1
  for (int i = 1; i < 31; ++i) if (e0 >= tab.off[i]) s = i;
  unsigned rel = e0 - tab.off[s];
  const float* sp = tab.src[s] + rel;
  unsigned nn = tab.n[s];
  union { u16 h[8]; v8s v; } o;
  if (rel + 8 <= nn) {
    float4 a = *(const float4*)sp;
    float4 b = *(const float4*)(sp+4);
    o.h[0]=f2bf(a.x); o.h[1]=f2bf(a.y); o.h[2]=f2bf(a.z); o.h[3]=f2bf(a.w);
    o.h[4]=f2bf(b.x); o.h[5]=f2bf(b.y); o.h[6]=f2bf(b.z); o.h[7]=f2bf(b.w);
  } else {
#pragma unroll
    for (int k = 0; k < 8; ++k) o.h[k] = (rel + k < nn) ? f2bf(sp[k]) : (u16)0;
  }
  *(v8s*)(arena + e0) = o.v;
}

// ---------------------------------------------------------------------------
// Generic bf16 GEMM: C[M][N] = A[M][K] @ B[N][K]^T (+bias1+bias2)(+tanh)(+C)
// GF_XGN: write bf16 at [(row&511)*64 + (row>>9)]*2048 + col  ([t][n][2048])
// GF_GATHA: A row gather via Xidx (embedding rows)
// ---------------------------------------------------------------------------
#define GF_OUTBF16 1
#define GF_TANH    2
#define GF_ACCUM   4
#define GF_XGN     8
#define GF_GATHA   16

__global__ __launch_bounds__(256) void gemm_bf16(
    const u16* __restrict__ A, long long lda,
    const u16* __restrict__ B,
    const u16* __restrict__ bias1, const u16* __restrict__ bias2,
    void* __restrict__ Cout, long long ldc,
    int M, int Nn, int K, int flags, const int* __restrict__ Xidx)
{
  __shared__ u16 As[8192];
  __shared__ u16 Bs[8192];
  int tid = threadIdx.x;
  int lane = tid & 63, w = tid >> 6;
  int wm = w >> 1, wn = w & 1;
  int bm = blockIdx.x * 128, bn = blockIdx.y * 128;

  v4f acc[4][4];
#pragma unroll
  for (int i=0;i<4;++i)
#pragma unroll
    for (int j=0;j<4;++j) acc[i][j] = (v4f){0.f,0.f,0.f,0.f};

#pragma unroll 1
  for (int ko = 0; ko < K; ko += 64) {
    __syncthreads();
#pragma unroll
    for (int it = 0; it < 8; ++it) {
      int c = tid + 256*it;
      int half = c >> 10;
      int cc = c & 1023;
      int r = cc >> 3;
      int kcb = cc & 7;
      const u16* src;
      if (half == 0) {
        int row = min(bm + r, M-1);
        long long ar = (flags & GF_GATHA) ? (long long)Xidx[row] : (long long)row;
        src = A + (size_t)ar*(size_t)lda + ko + (kcb<<3);
      } else {
        int row = min(bn + r, Nn-1);
        src = B + (size_t)row*(size_t)K + ko + (kcb<<3);
      }
      v8s v = *(const v8s*)src;
      char* base = (char*)(half ? Bs : As);
      *(v8s*)(base + (r<<7) + ((kcb<<4) ^ ((r&7)<<4))) = v;
    }
    __syncthreads();
#pragma unroll
    for (int ks = 0; ks < 2; ++ks) {
      v8s af[4], bfr[4];
#pragma unroll
      for (int mt=0; mt<4; ++mt) {
        int r = wm*64 + mt*16 + (lane & 15);
        int kb = (ks<<6) + ((lane>>4)<<4);
        af[mt] = *(const v8s*)((const char*)As + (r<<7) + (kb ^ ((r&7)<<4)));
      }
#pragma unroll
      for (int nt=0; nt<4; ++nt) {
        int r = wn*64 + nt*16 + (lane & 15);
        int kb = (ks<<6) + ((lane>>4)<<4);
        bfr[nt] = *(const v8s*)((const char*)Bs + (r<<7) + (kb ^ ((r&7)<<4)));
      }
#pragma unroll
      for (int mt=0; mt<4; ++mt)
#pragma unroll
        for (int nt=0; nt<4; ++nt)
          acc[mt][nt] = __builtin_amdgcn_mfma_f32_16x16x32_bf16(af[mt], bfr[nt], acc[mt][nt], 0,0,0);
    }
  }

#pragma unroll
  for (int mt=0; mt<4; ++mt) {
#pragma unroll
    for (int nt=0; nt<4; ++nt) {
      int col = bn + wn*64 + nt*16 + (lane&15);
      if (col >= Nn) continue;
      float b = 0.f;
      if (bias1) b += bf2f(bias1[col]);
      if (bias2) b += bf2f(bias2[col]);
#pragma unroll
      for (int r=0; r<4; ++r) {
        int row = bm + wm*64 + mt*16 + ((lane>>4)<<2) + r;
        if (row >= M) continue;
        float v = acc[mt][nt][r] + b;
        if (flags & GF_XGN) {
          ((u16*)Cout)[((size_t)(row&511)*64 + (row>>9))*2048 + col] = f2bf(v);
        } else {
          if (flags & GF_ACCUM) v += ((float*)Cout)[(size_t)row*(size_t)ldc + col];
          if (flags & GF_TANH) v = ftanh(v);
          if (flags & GF_OUTBF16) ((u16*)Cout)[(size_t)row*(size_t)ldc + col] = f2bf(v);
          else                    ((float*)Cout)[(size_t)row*(size_t)ldc + col] = v;
        }
      }
    }
  }
}

// ---------------------------------------------------------------------------
// Persistent bidirectional LSTM scan, pure-recurrent when XG (input projections
// precomputed as xg[dir][t][n][2048] incl. biases).
// 32 blocks: dir = blk>>4, ug = blk&15 (32 units). 4 waves = 4 gates.
// h_prev staged in LDS once per block (pad-1040 rows, <=2-way bank reads).
// Whh slice VGPR-pinned. Write-through h stores; plain staged loads (every
// hbuf line written exactly once, read first time by any consumer cache).
// Per-wave arrival: s_waitcnt vmcnt(0) + 1 atomicAdd; poll target 64*step.
// ---------------------------------------------------------------------------
template<bool XG, int LAYER>
__global__ __launch_bounds__(256, 1) void lstm_scan(
    const u16* __restrict__ xsrc,      // fallback: L0 embW ; L1 h0
    const int* __restrict__ Xidx,      // fallback L0 only
    const u16* __restrict__ Wih_f, const u16* __restrict__ Wih_b,
    const u16* __restrict__ Whh_f, const u16* __restrict__ Whh_b,
    const u16* __restrict__ bih_f, const u16* __restrict__ bhh_f,
    const u16* __restrict__ bih_b, const u16* __restrict__ bhh_b,
    const u16* __restrict__ xg,        // XG: [2][512][64][2048]
    u16* __restrict__ hbuf,            // [64][512][1024] layer output
    unsigned* __restrict__ bar)
{
  __shared__ u16   hstage[64*520];     // 64 rows x 1040B (pad 16B)
  __shared__ float glds[4*64*34];
  __shared__ u16   hlds[2048];

  const int tid = threadIdx.x, lane = tid & 63, w = tid >> 6;
  const int dir = blockIdx.x >> 4, ug = blockIdx.x & 15;
  const u16* Whh = dir ? Whh_b : Whh_f;
  unsigned* cnt = bar + dir*64;

  const int an = lane & 15;
  const int ak = (lane >> 4) << 3;

  // ---- Whh slice pinned in VGPRs ----
  v8s whh_reg[2][16];
#pragma unroll
  for (int nt = 0; nt < 2; ++nt) {
    const u16* wp = Whh + (size_t)((w*512 + ug*32 + nt*16 + an))*512;
#pragma unroll
    for (int kc = 0; kc < 16; ++kc) {
      whh_reg[nt][kc] = *(const v8s*)(wp + kc*32 + ak);
      asm volatile("" : "+v"(whh_reg[nt][kc]));
    }
  }

  const int u_pw = tid & 31, uj_pw = ug*32 + u_pw;
  float creg[8];
#pragma unroll
  for (int i = 0; i < 8; ++i) creg[i] = 0.f;

  if constexpr (XG) {
    const int nb = (tid >> 5) * 8;     // 8 consecutive batches per pw-thread
    const u16* xgd = xg + (size_t)dir*67108864;

    for (int step = 0; step < 512; ++step) {
      const int t     = dir ? (511 - step) : step;
      const int tprev = dir ? (t + 1) : (t - 1);

      // ---- early xg reads (independent of h_prev) ----
      float xga[4][8];
#pragma unroll
      for (int q = 0; q < 4; ++q)
#pragma unroll
        for (int it = 0; it < 8; ++it)
          xga[q][it] = bf2f(xgd[((size_t)t*64 + nb + it)*2048 + q*512 + uj_pw]);

      v4f acc[4][2];
#pragma unroll
      for (int i=0;i<4;++i){ acc[i][0]=(v4f){0,0,0,0}; acc[i][1]=(v4f){0,0,0,0}; }

      if (step > 0) {
        if (tid == 0) {
          unsigned tgt = 64u*(unsigned)step;
          while (__hip_atomic_load(cnt, __ATOMIC_RELAXED, __HIP_MEMORY_SCOPE_AGENT) < tgt)
            __builtin_amdgcn_s_sleep(1);
        }
        __syncthreads();
        // ---- cooperative h_prev stage: 64KB, coalesced, deep pipeline ----
        {
          const u16* rb = hbuf + (((size_t)((tid>>2)*512 + tprev)) << 10) + dir*512 + (tid&3)*128;
          char* dst = (char*)hstage + (tid>>2)*1040 + (tid&3)*256;
#pragma unroll
          for (int c = 0; c < 16; ++c)
            *(v8s*)(dst + c*16) = *(const v8s*)(rb + c*8);
        }
        __syncthreads();
        // ---- recurrent MFMA from LDS ----
#pragma unroll
        for (int kc = 0; kc < 16; ++kc) {
          v8s af[4];
#pragma unroll
          for (int mt = 0; mt < 4; ++mt)
            af[mt] = *(const v8s*)((const char*)hstage + (size_t)(mt*16+an)*1040 + kc*64 + ak*2);
#pragma unroll
          for (int nt = 0; nt < 2; ++nt)
#pragma unroll
            for (int mt = 0; mt < 4; ++mt)
              acc[mt][nt] = __builtin_amdgcn_mfma_f32_16x16x32_bf16(af[mt], whh_reg[nt][kc], acc[mt][nt], 0,0,0);
        }
      }

      // ---- exchange gates across waves ----
#pragma unroll
      for (int mt=0; mt<4; ++mt)
#pragma unroll
        for (int nt=0; nt<2; ++nt)
#pragma unroll
          for (int r4=0; r4<4; ++r4) {
            int n = mt*16 + ((lane>>4)<<2) + r4;
            int u = nt*16 + an;
            glds[w*2176 + n*34 + u] = acc[mt][nt][r4];
          }
      __syncthreads();

      // ---- pointwise (gates = MFMA partials + xg) ----
#pragma unroll
      for (int it = 0; it < 8; ++it) {
        int n = nb + it;
        float g0 = glds[0*2176 + n*34 + u_pw] + xga[0][it];
        float g1 = glds[1*2176 + n*34 + u_pw] + xga[1][it];
        float g2 = glds[2*2176 + n*34 + u_pw] + xga[2][it];
        float g3 = glds[3*2176 + n*34 + u_pw] + xga[3][it];
        float cn = sigm(g1)*creg[it] + sigm(g0)*ftanh(g2);
        creg[it] = cn;
        hlds[n*32 + u_pw] = f2bf(sigm(g3)*ftanh(cn));
      }
      __syncthreads();

      // ---- packed write-through store + per-wave arrival ----
      {
        int n  = tid >> 2;
        int ub = (tid & 3) << 3;
        u64 a = *(const u64*)&hlds[n*32 + ub];
        u64 b = *(const u64*)&hlds[n*32 + ub + 4];
        store_h16(hbuf + ((size_t)(n*512 + t) << 10) + dir*512 + ug*32 + ub, a, b);
      }
      asm volatile("s_waitcnt vmcnt(0)" ::: "memory");
      if ((tid & 63) == 0)
        __hip_atomic_fetch_add(cnt, 1u, __ATOMIC_RELAXED, __HIP_MEMORY_SCOPE_AGENT);
    }
    return;
  }

  // ================= fallback path (ws too small for xg) ==================
  constexpr int NCX = (LAYER==0) ? 4 : 32;
  constexpr int KX  = NCX*32;
  const u16* Wih = dir ? Wih_b : Wih_f;
  const u16* wihp[2];
#pragma unroll
  for (int nt = 0; nt < 2; ++nt)
    wihp[nt] = Wih + (size_t)(w*512 + ug*32 + nt*16 + an)*KX;

  v8s wih0[2][(LAYER==0)?4:1];
  if constexpr (LAYER == 0) {
#pragma unroll
    for (int nt = 0; nt < 2; ++nt)
#pragma unroll
      for (int kc = 0; kc < 4; ++kc) {
        wih0[nt][kc] = *(const v8s*)(wihp[nt] + kc*32 + ak);
        asm volatile("" : "+v"(wih0[nt][kc]));
      }
  }
  float bsum[4];
  {
    const u16* bi = dir ? bih_b : bih_f;
    const u16* bh = dir ? bhh_b : bhh_f;
#pragma unroll
    for (int q = 0; q < 4; ++q)
      bsum[q] = bf2f(bi[q*512 + uj_pw]) + bf2f(bh[q*512 + uj_pw]);
  }

  for (int step = 0; step < 512; ++step) {
    const int t     = dir ? (511 - step) : step;
    const int tprev = dir ? (t + 1) : (t - 1);

    v4f acc[4][2];
#pragma unroll
    for (int i=0;i<4;++i){ acc[i][0]=(v4f){0,0,0,0}; acc[i][1]=(v4f){0,0,0,0}; }

    {
      const u16* arow[4];
#pragma unroll
      for (int mt = 0; mt < 4; ++mt) {
        if constexpr (LAYER == 0) {
          int xr = Xidx[(mt*16 + an)*512 + t];
          arow[mt] = xsrc + (size_t)xr * 128;
        } else {
          arow[mt] = xsrc + ((size_t)((mt*16 + an)*512 + t) << 10);
        }
      }
#pragma unroll
      for (int kc = 0; kc < NCX; ++kc) {
        v8s af[4];
#pragma unroll
        for (int mt = 0; mt < 4; ++mt) af[mt] = *(const v8s*)(arow[mt] + kc*32 + ak);
#pragma unroll
        for (int nt = 0; nt < 2; ++nt) {
          v8s bfr;
          if constexpr (LAYER == 0) bfr = wih0[nt][kc];
          else                      bfr = *(const v8s*)(wihp[nt] + kc*32 + ak);
#pragma unroll
          for (int mt = 0; mt < 4; ++mt)
            acc[mt][nt] = __builtin_amdgcn_mfma_f32_16x16x32_bf16(af[mt], bfr, acc[mt][nt], 0,0,0);
        }
      }
    }

    if (step > 0) {
      if (tid == 0) {
        unsigned tgt = 64u*(unsigned)step;
        while (__hip_atomic_load(cnt, __ATOMIC_RELAXED, __HIP_MEMORY_SCOPE_AGENT) < tgt)
          __builtin_amdgcn_s_sleep(1);
      }
      __syncthreads();
      asm volatile("" ::: "memory");
      const u16* hrow[4];
#pragma unroll
      for (int mt = 0; mt < 4; ++mt)
        hrow[mt] = hbuf + ((size_t)((mt*16 + an)*512 + tprev) << 10) + dir*512;
#pragma unroll
      for (int kc = 0; kc < 16; ++kc) {
        v8s af[4];
#pragma unroll
        for (int mt = 0; mt < 4; ++mt) af[mt] = *(const v8s*)(hrow[mt] + kc*32 + ak);
#pragma unroll
        for (int nt = 0; nt < 2; ++nt)
#pragma unroll
          for (int mt = 0; mt < 4; ++mt)
            acc[mt][nt] = __builtin_amdgcn_mfma_f32_16x16x32_bf16(af[mt], whh_reg[nt][kc], acc[mt][nt], 0,0,0);
      }
    }

#pragma unroll
    for (int mt=0; mt<4; ++mt)
#pragma unroll
      for (int nt=0; nt<2; ++nt)
#pragma unroll
        for (int r4=0; r4<4; ++r4) {
          int n = mt*16 + ((lane>>4)<<2) + r4;
          int u = nt*16 + an;
          glds[w*2176 + n*34 + u] = acc[mt][nt][r4];
        }
    __syncthreads();

#pragma unroll
    for (int it = 0; it < 8; ++it) {
      int n = (tid >> 5) + it*8;
      float g0 = glds[0*2176 + n*34 + u_pw] + bsum[0];
      float g1 = glds[1*2176 + n*34 + u_pw] + bsum[1];
      float g2 = glds[2*2176 + n*34 + u_pw] + bsum[2];
      float g3 = glds[3*2176 + n*34 + u_pw] + bsum[3];
      float cn = sigm(g1)*creg[it] + sigm(g0)*ftanh(g2);
      creg[it] = cn;
      hlds[n*32 + u_pw] = f2bf(sigm(g3)*ftanh(cn));
    }
    __syncthreads();

    {
      int n  = tid >> 2;
      int ub = (tid & 3) << 3;
      u64 a = *(const u64*)&hlds[n*32 + ub];
      u64 b = *(const u64*)&hlds[n*32 + ub + 4];
      store_h16(hbuf + ((size_t)(n*512 + t) << 10) + dir*512 + ug*32 + ub, a, b);
    }
    asm volatile("s_waitcnt vmcnt(0)" ::: "memory");
    if ((tid & 63) == 0)
      __hip_atomic_fetch_add(cnt, 1u, __ATOMIC_RELAXED, __HIP_MEMORY_SCOPE_AGENT);
  }
}

// ---------------------------------------------------------------------------
// Fused attention step
// ---------------------------------------------------------------------------
__global__ __launch_bounds__(256) void attn_step(
    const float* __restrict__ qbuf, const u16* __restrict__ Uah,
    const u16* __restrict__ hid, const int* __restrict__ seq_len,
    const u16* __restrict__ vaW, const u16* __restrict__ vab,
    u16* __restrict__ catb)
{
  int n = blockIdx.x, tid = threadIdx.x;
  __shared__ float qs[1024];
  __shared__ float vas[1024];
  __shared__ float es[512];
  __shared__ float red[8];
  for (int d=tid; d<1024; d+=256){ qs[d]=qbuf[n*1024+d]; vas[d]=bf2f(vaW[d]); }
  __syncthreads();
  int sl = seq_len[n];
  float vb = bf2f(vab[0]);
  for (int l=tid; l<512; l+=256) {
    const u16* up = Uah + ((size_t)n*512 + l)*1024;
    float a = 0.f;
    for (int d=0; d<1024; d+=8) {
      v8s uv = *(const v8s*)(up + d);
#pragma unroll
      for (int e=0;e<8;++e)
        a = fmaf(ftanh(bf2f((u16)uv[e]) + qs[d+e]), vas[d+e], a);
    }
    float ev = a + vb;
    if (l >= sl) ev += NEG_INF;
    es[l] = ev;
  }
  __syncthreads();
  float m = -3.4e38f;
  for (int l=tid; l<512; l+=256) m = fmaxf(m, es[l]);
#pragma unroll
  for (int off=1; off<64; off<<=1) m = fmaxf(m, __shfl_xor(m, off));
  if ((tid&63)==0) red[tid>>6] = m;
  __syncthreads();
  m = fmaxf(fmaxf(red[0],red[1]), fmaxf(red[2],red[3]));
  float s = 0.f;
  for (int l=tid; l<512; l+=256){ float p = __expf(es[l]-m); es[l]=p; s+=p; }
#pragma unroll
  for (int off=1; off<64; off<<=1) s += __shfl_xor(s, off);
  if ((tid&63)==0) red[4+(tid>>6)] = s;
  __syncthreads();
  float inv = 1.f/(red[4]+red[5]+red[6]+red[7]);
  int d0 = tid*4;
  float c0=0,c1=0,c2=0,c3=0;
  for (int l=0; l<512; ++l) {
    float a = es[l];
    const u16* hp = hid + ((size_t)n*512 + l)*1024 + d0;
    v4s hv = *(const v4s*)hp;
    c0 = fmaf(a, bf2f((u16)hv[0]), c0);
    c1 = fmaf(a, bf2f((u16)hv[1]), c1);
    c2 = fmaf(a, bf2f((u16)hv[2]), c2);
    c3 = fmaf(a, bf2f((u16)hv[3]), c3);
  }
  catb[n*2048 + d0 + 0] = f2bf(c0*inv);
  catb[n*2048 + d0 + 1] = f2bf(c1*inv);
  catb[n*2048 + d0 + 2] = f2bf(c2*inv);
  catb[n*2048 + d0 + 3] = f2bf(c3*inv);
}

__global__ void dec_pw(const float* __restrict__ g, u16* __restrict__ scat,
                       u16* __restrict__ catb, int it)
{
  int idx = blockIdx.x*256 + threadIdx.x;
  int n = idx >> 10, d = idx & 1023;
  float gi = g[(size_t)n*4096 + d];
  float gg = g[(size_t)n*4096 + 2048 + d];
  float go = g[(size_t)n*4096 + 3072 + d];
  float c = sigm(gi)*ftanh(gg);
  float s = sigm(go)*ftanh(c);
  u16 hb = f2bf(s);
  scat[((size_t)n*11 + it)*1024 + d] = hb;
  catb[n*2048 + 1024 + d] = hb;
}

__global__ void fill_sentinel(float* out, int nel){
  int i = blockIdx.x*256 + threadIdx.x;
  if (i < nel) out[i] = 12345.0f;
}

// ---------------------------------------------------------------------------
extern "C" void kernel_launch(void* const* d_in, const int* in_sizes, int n_in,
                              void* d_out, int out_size, void* d_ws, size_t ws_size,
                              hipStream_t stream)
{
  const int* X      = (const int*)d_in[0];
  const int* seqlen = (const int*)d_in[1];
  float* out = (float*)d_out;
  char* ws = (char*)d_ws;

  struct Seg { int idx; int n; };
  static const Seg segs[31] = {
    {2, 4096000},
    {3, 262144},{4,1048576},{5,2048},{6,2048},
    {7, 262144},{8,1048576},{9,2048},{10,2048},
    {11,2097152},{12,1048576},{13,2048},{14,2048},
    {15,2097152},{16,1048576},{17,2048},{18,2048},
    {19,1048576},{20,1024},
    {21,1048576},{22,1024},
    {23,1048576},{24,1024},
    {25,1024},{26,1},
    {27,4194304},{28,4194304},{29,4096},{30,4096},
    {31,10240000},{32,10000},
  };
  const u16* bp[33];
  CvtTab tab;
  size_t aoff = 0;
  for (int i = 0; i < 31; ++i) {
    bp[segs[i].idx] = (const u16*)(ws) + aoff;
    tab.src[i] = (const float*)d_in[segs[i].idx];
    tab.off[i] = (unsigned)aoff;
    tab.n[i]   = (unsigned)segs[i].n;
    aoff += (size_t)((segs[i].n + 7) & ~7);
  }
  tab.total = (unsigned)aoff;
  size_t arena_bytes = ((aoff*2 + 255) & ~(size_t)255);

  const size_t H0_OFF   = arena_bytes;
  const size_t HID_OFF  = H0_OFF   + 67108864;
  const size_t BAR_OFF  = HID_OFF  + 67108864;
  const size_t CATB_OFF = BAR_OFF  + 1024;
  const size_t QBUF_OFF = CATB_OFF + 262144;
  const size_t GDEC_OFF = QBUF_OFF + 262144;
  const size_t SCAT_OFF = GDEC_OFF + 1048576;
  const size_t XG_OFF   = SCAT_OFF + 1441792;       // 16B-aligned
  const size_t NEED     = XG_OFF;                    // fallback requirement
  const size_t NEED_BIG = XG_OFF + 268435456ull;     // + xg[2][512][64][2048]

  if (ws_size < NEED) {
    fill_sentinel<<<(out_size+255)/256, 256, 0, stream>>>(out, out_size);
    return;
  }
  const bool big = (ws_size >= NEED_BIG);

  u16*      h0   = (u16*)(ws + H0_OFF);
  u16*      hid  = (u16*)(ws + HID_OFF);
  unsigned* bar  = (unsigned*)(ws + BAR_OFF);
  u16*      catb = (u16*)(ws + CATB_OFF);
  float*    qbuf = (float*)(ws + QBUF_OFF);
  float*    gdec = (float*)(ws + GDEC_OFF);
  u16*      scat = (u16*)(ws + SCAT_OFF);
  u16*      xg   = (u16*)(ws + XG_OFF);
  u16*      Uah  = big ? (u16*)(ws + XG_OFF) : (u16*)(ws + H0_OFF); // alias dead bufs

  hipMemsetAsync(ws + BAR_OFF, 0, 1024, stream);

  {
    unsigned nth = (unsigned)(aoff / 8);
    cvt_all<<<(nth + 255)/256, 256, 0, stream>>>(tab, (u16*)ws);
  }

  if (big) {
    // xg0 = embW[X] @ Wih0^T + bih + bhh   (both dirs)
    gemm_bf16<<<dim3(256,16), 256, 0, stream>>>(bp[2], 128, bp[3], bp[5], bp[6],
        xg, 0, 32768, 2048, 128, GF_XGN|GF_GATHA, X);
    gemm_bf16<<<dim3(256,16), 256, 0, stream>>>(bp[2], 128, bp[7], bp[9], bp[10],
        xg + 67108864, 0, 32768, 2048, 128, GF_XGN|GF_GATHA, X);
    lstm_scan<true,0><<<32, 256, 0, stream>>>(
        nullptr, nullptr, nullptr, nullptr, bp[4], bp[8],
        nullptr, nullptr, nullptr, nullptr, xg, h0, bar);
    // xg1 = h0 @ Wih1^T + bih + bhh
    gemm_bf16<<<dim3(256,16), 256, 0, stream>>>(h0, 1024, bp[11], bp[13], bp[14],
        xg, 0, 32768, 2048, 1024, GF_XGN, nullptr);
    gemm_bf16<<<dim3(256,16), 256, 0, stream>>>(h0, 1024, bp[15], bp[17], bp[18],
        xg + 67108864, 0, 32768, 2048, 1024, GF_XGN, nullptr);
    lstm_scan<true,1><<<32, 256, 0, stream>>>(
        nullptr, nullptr, nullptr, nullptr, bp[12], bp[16],
        nullptr, nullptr, nullptr, nullptr, xg, hid, bar + 128);
  } else {
    lstm_scan<false,0><<<32, 256, 0, stream>>>(
        bp[2], X, bp[3], bp[7], bp[4], bp[8],
        bp[5], bp[6], bp[9], bp[10], nullptr, h0, bar);
    lstm_scan<false,1><<<32, 256, 0, stream>>>(
        h0, nullptr, bp[11], bp[15], bp[12], bp[16],
        bp[13], bp[14], bp[17], bp[18], nullptr, hid, bar + 128);
  }

  // ---- attention precompute ----
  gemm_bf16<<<dim3(256,8), 256, 0, stream>>>(hid, 1024, bp[23], bp[24], nullptr,
      Uah, 1024, 32768, 1024, 1024, GF_OUTBF16, nullptr);
  gemm_bf16<<<dim3(1,8), 256, 0, stream>>>(hid, 524288, bp[19], bp[20], nullptr,
      catb + 1024, 2048, 64, 1024, 1024, GF_OUTBF16 | GF_TANH, nullptr);

  // ---- 11 decoder steps ----
  for (int it = 0; it < 11; ++it) {
    gemm_bf16<<<dim3(1,8), 256, 0, stream>>>(catb + 1024, 2048, bp[21], bp[22], nullptr,
        qbuf, 1024, 64, 1024, 1024, 0, nullptr);
    attn_step<<<64, 256, 0, stream>>>(qbuf, Uah, hid, seqlen, bp[25], bp[26], catb);
    gemm_bf16<<<dim3(1,32), 256, 0, stream>>>(catb, 2048, bp[27], bp[29], bp[30],
        gdec, 4096, 64, 4096, 1024, 0, nullptr);
    gemm_bf16<<<dim3(1,32), 256, 0, stream>>>(catb + 1024, 2048, bp[28], nullptr, nullptr,
        gdec, 4096, 64, 4096, 1024, GF_ACCUM, nullptr);
    dec_pw<<<256, 256, 0, stream>>>(gdec, scat, catb, it);
  }

  // ---- classifier (f32 output) ----
  gemm_bf16<<<dim3(6,79), 256, 0, stream>>>(scat, 1024, bp[31], bp[32], nullptr,
      out, 10000, 704, 10000, 1024, 0, nullptr);
}

// Round 7
// 13329.820 us; speedup vs baseline: 2.1313x; 2.1313x over previous
//
#include <hip/hip_runtime.h>
#include <stdint.h>

#define NEG_INF -100000000.0f

typedef unsigned short u16;
typedef unsigned long long u64;
typedef __attribute__((ext_vector_type(8))) short v8s;
typedef __attribute__((ext_vector_type(4))) short v4s;
typedef __attribute__((ext_vector_type(4))) float v4f;

__device__ __forceinline__ float bf2f(u16 h){ return __uint_as_float(((unsigned)h)<<16); }
__device__ __forceinline__ u16 f2bf(float f){
  unsigned u = __float_as_uint(f);
  u = u + 0x7fffu + ((u>>16)&1u);
  return (u16)(u>>16);
}
__device__ __forceinline__ float sigm(float x){ return 1.0f/(1.0f+__expf(-x)); }
__device__ __forceinline__ float ftanh(float x){
  x = fminf(15.0f, fmaxf(-15.0f, x));
  float e = __expf(2.0f*x);
  return (e-1.0f)/(e+1.0f);
}

// write-through (coherence-point) 16B h store; consumer loads are PLAIN
__device__ __forceinline__ void store_h16(u16* p, u64 a, u64 b){
  __hip_atomic_store((u64*)p,     a, __ATOMIC_RELAXED, __HIP_MEMORY_SCOPE_AGENT);
  __hip_atomic_store((u64*)(p+4), b, __ATOMIC_RELAXED, __HIP_MEMORY_SCOPE_AGENT);
}

// ---------------------------------------------------------------------------
// Fused f32 -> bf16 arena conversion
// ---------------------------------------------------------------------------
struct CvtTab {
  const float* src[31];
  unsigned off[31];
  unsigned n[31];
  unsigned total;
};

__global__ __launch_bounds__(256) void cvt_all(CvtTab tab, u16* __restrict__ arena){
  unsigned e0 = (blockIdx.x*256u + threadIdx.x)*8u;
  if (e0 >= tab.total) return;
  int s = 0;
#pragma unroll 1
  for (int i = 1; i < 31; ++i) if (e0 >= tab.off[i]) s = i;
  unsigned rel = e0 - tab.off[s];
  const float* sp = tab.src[s] + rel;
  unsigned nn = tab.n[s];
  union { u16 h[8]; v8s v; } o;
  if (rel + 8 <= nn) {
    float4 a = *(const float4*)sp;
    float4 b = *(const float4*)(sp+4);
    o.h[0]=f2bf(a.x); o.h[1]=f2bf(a.y); o.h[2]=f2bf(a.z); o.h[3]=f2bf(a.w);
    o.h[4]=f2bf(b.x); o.h[5]=f2bf(b.y); o.h[6]=f2bf(b.z); o.h[7]=f2bf(b.w);
  } else {
#pragma unroll
    for (int k = 0; k < 8; ++k) o.h[k] = (rel + k < nn) ? f2bf(sp[k]) : (u16)0;
  }
  *(v8s*)(arena + e0) = o.v;
}

// ---------------------------------------------------------------------------
// Generic bf16 GEMM: C[M][N] = A[M][K] @ B[N][K]^T (+bias1+bias2)(+tanh)(+C)
// ---------------------------------------------------------------------------
#define GF_OUTBF16 1
#define GF_TANH    2
#define GF_ACCUM   4

__global__ __launch_bounds__(256) void gemm_bf16(
    const u16* __restrict__ A, long long lda,
    const u16* __restrict__ B,
    const u16* __restrict__ bias1, const u16* __restrict__ bias2,
    void* __restrict__ Cout, long long ldc,
    int M, int Nn, int K, int flags)
{
  __shared__ u16 As[8192];
  __shared__ u16 Bs[8192];
  int tid = threadIdx.x;
  int lane = tid & 63, w = tid >> 6;
  int wm = w >> 1, wn = w & 1;
  int bm = blockIdx.x * 128, bn = blockIdx.y * 128;

  v4f acc[4][4];
#pragma unroll
  for (int i=0;i<4;++i)
#pragma unroll
    for (int j=0;j<4;++j) acc[i][j] = (v4f){0.f,0.f,0.f,0.f};

#pragma unroll 1
  for (int ko = 0; ko < K; ko += 64) {
    __syncthreads();
#pragma unroll
    for (int it = 0; it < 8; ++it) {
      int c = tid + 256*it;
      int half = c >> 10;
      int cc = c & 1023;
      int r = cc >> 3;
      int kcb = cc & 7;
      const u16* src;
      if (half == 0) {
        int row = min(bm + r, M-1);
        src = A + (size_t)row*(size_t)lda + ko + (kcb<<3);
      } else {
        int row = min(bn + r, Nn-1);
        src = B + (size_t)row*(size_t)K + ko + (kcb<<3);
      }
      v8s v = *(const v8s*)src;
      char* base = (char*)(half ? Bs : As);
      *(v8s*)(base + (r<<7) + ((kcb<<4) ^ ((r&7)<<4))) = v;
    }
    __syncthreads();
#pragma unroll
    for (int ks = 0; ks < 2; ++ks) {
      v8s af[4], bfr[4];
#pragma unroll
      for (int mt=0; mt<4; ++mt) {
        int r = wm*64 + mt*16 + (lane & 15);
        int kb = (ks<<6) + ((lane>>4)<<4);
        af[mt] = *(const v8s*)((const char*)As + (r<<7) + (kb ^ ((r&7)<<4)));
      }
#pragma unroll
      for (int nt=0; nt<4; ++nt) {
        int r = wn*64 + nt*16 + (lane & 15);
        int kb = (ks<<6) + ((lane>>4)<<4);
        bfr[nt] = *(const v8s*)((const char*)Bs + (r<<7) + (kb ^ ((r&7)<<4)));
      }
#pragma unroll
      for (int mt=0; mt<4; ++mt)
#pragma unroll
        for (int nt=0; nt<4; ++nt)
          acc[mt][nt] = __builtin_amdgcn_mfma_f32_16x16x32_bf16(af[mt], bfr[nt], acc[mt][nt], 0,0,0);
    }
  }

#pragma unroll
  for (int mt=0; mt<4; ++mt) {
#pragma unroll
    for (int nt=0; nt<4; ++nt) {
      int col = bn + wn*64 + nt*16 + (lane&15);
      if (col >= Nn) continue;
      float b = 0.f;
      if (bias1) b += bf2f(bias1[col]);
      if (bias2) b += bf2f(bias2[col]);
#pragma unroll
      for (int r=0; r<4; ++r) {
        int row = bm + wm*64 + mt*16 + ((lane>>4)<<2) + r;
        if (row >= M) continue;
        float v = acc[mt][nt][r] + b;
        if (flags & GF_ACCUM) v += ((float*)Cout)[(size_t)row*(size_t)ldc + col];
        if (flags & GF_TANH) v = ftanh(v);
        if (flags & GF_OUTBF16) ((u16*)Cout)[(size_t)row*(size_t)ldc + col] = f2bf(v);
        else                    ((float*)Cout)[(size_t)row*(size_t)ldc + col] = v;
      }
    }
  }
}

// ---------------------------------------------------------------------------
// Persistent bidirectional LSTM scan, (K-half x gate-pair) wave split.
// 64 blocks: dir = blk>>5, ug = blk&31 (16 units each). Wave w: kh=w>>1 owns
// K-half, gp=w&1 owns gate pair {2gp, 2gp+1}. ALL weights VGPR-pinned
// (Wih slice 2x(K/2) + Whh slice 2x256 per wave). A-fragments (x, h_prev)
// load global->VGPR plain (pipelined); the two gp-waves of a kh read
// identical addresses -> L1 serves the duplicate.
// Gate partials from both kh-halves summed via glds in the pointwise.
// Coherence: write-through relaxed-atomic 16B h stores (LLC = coherence
// point, merges partial lines); consumer plain loads touch each line only
// after the producers' arrivals -> never stale. Relaxed counter barrier,
// 4 arrivals/block, target 128/step per dir.
// ---------------------------------------------------------------------------
template<int LAYER>
__global__ __launch_bounds__(256, 1) void lstm_scan(
    const u16* __restrict__ xsrc,      // L0: embW ; L1: h0
    const int* __restrict__ Xidx,      // L0 only
    const u16* __restrict__ Wih_f, const u16* __restrict__ Wih_b,
    const u16* __restrict__ Whh_f, const u16* __restrict__ Whh_b,
    const u16* __restrict__ bih_f, const u16* __restrict__ bhh_f,
    const u16* __restrict__ bih_b, const u16* __restrict__ bhh_b,
    u16* __restrict__ hbuf,            // [64][512][1024] layer output
    unsigned* __restrict__ bar)
{
  constexpr int KX  = (LAYER==0) ? 128 : 1024;
  constexpr int NKC = KX/64;                 // x k-chunks per K-half (2 / 16)
  __shared__ float glds[8*64*17];            // [kh*4+gate][n][17]
  __shared__ u16   hlds[1024];               // [n][16u]

  const int tid = threadIdx.x, lane = tid & 63, w = tid >> 6;
  const int kh = w >> 1, gp = w & 1;
  const int dir = blockIdx.x >> 5, ug = blockIdx.x & 31;
  const int an = lane & 15, hi = lane >> 4;
  const int ak = hi << 3;
  const u16* Wih = dir ? Wih_b : Wih_f;
  const u16* Whh = dir ? Whh_b : Whh_f;
  unsigned* cnt = bar + dir*64;

  // ---- weights pinned in VGPRs ----
  v8s wih_reg[2][NKC];
#pragma unroll
  for (int gg = 0; gg < 2; ++gg) {
    const u16* wp = Wih + (size_t)((gp*2+gg)*512 + ug*16 + an)*KX + kh*(KX/2);
#pragma unroll
    for (int kc = 0; kc < NKC; ++kc) {
      wih_reg[gg][kc] = *(const v8s*)(wp + kc*32 + ak);
      asm volatile("" : "+v"(wih_reg[gg][kc]));
    }
  }
  v8s whh_reg[2][8];
#pragma unroll
  for (int gg = 0; gg < 2; ++gg) {
    const u16* wp = Whh + (size_t)((gp*2+gg)*512 + ug*16 + an)*512 + kh*256;
#pragma unroll
    for (int kc = 0; kc < 8; ++kc) {
      whh_reg[gg][kc] = *(const v8s*)(wp + kc*32 + ak);
      asm volatile("" : "+v"(whh_reg[gg][kc]));
    }
  }

  const int u_pw = tid & 15, nb_pw = tid >> 4;   // thread owns unit u_pw, n = nb_pw+16k
  const int uj_pw = ug*16 + u_pw;
  float bsum[4];
  {
    const u16* bi = dir ? bih_b : bih_f;
    const u16* bh = dir ? bhh_b : bhh_f;
#pragma unroll
    for (int q = 0; q < 4; ++q)
      bsum[q] = bf2f(bi[q*512 + uj_pw]) + bf2f(bh[q*512 + uj_pw]);
  }
  float creg[4] = {0.f, 0.f, 0.f, 0.f};

  for (int step = 0; step < 512; ++step) {
    const int t     = dir ? (511 - step) : step;
    const int tprev = dir ? (t + 1) : (t - 1);

    v4f acc[4][2];
#pragma unroll
    for (int i=0;i<4;++i){ acc[i][0]=(v4f){0,0,0,0}; acc[i][1]=(v4f){0,0,0,0}; }

    // ---- x-projection (independent of h_prev; overlaps producers) ----
    {
      const u16* xrow[4];
#pragma unroll
      for (int mt = 0; mt < 4; ++mt) {
        if constexpr (LAYER == 0)
          xrow[mt] = xsrc + (size_t)Xidx[(mt*16 + an)*512 + t]*128 + kh*64;
        else
          xrow[mt] = xsrc + ((size_t)((mt*16 + an)*512 + t) << 10) + kh*512;
      }
#pragma unroll
      for (int kc = 0; kc < NKC; ++kc) {
        v8s af[4];
#pragma unroll
        for (int mt = 0; mt < 4; ++mt) af[mt] = *(const v8s*)(xrow[mt] + kc*32 + ak);
#pragma unroll
        for (int gg = 0; gg < 2; ++gg)
#pragma unroll
          for (int mt = 0; mt < 4; ++mt)
            acc[mt][gg] = __builtin_amdgcn_mfma_f32_16x16x32_bf16(af[mt], wih_reg[gg][kc], acc[mt][gg], 0,0,0);
      }
    }

    // ---- wait for previous step's h, then recurrent MFMA ----
    if (step > 0) {
      if (tid == 0) {
        unsigned tgt = 128u*(unsigned)step;
        while (__hip_atomic_load(cnt, __ATOMIC_RELAXED, __HIP_MEMORY_SCOPE_AGENT) < tgt)
          __builtin_amdgcn_s_sleep(1);
      }
      __syncthreads();
      asm volatile("" ::: "memory");

      const u16* hrow[4];
#pragma unroll
      for (int mt = 0; mt < 4; ++mt)
        hrow[mt] = hbuf + ((size_t)((mt*16 + an)*512 + tprev) << 10) + dir*512 + kh*256;
#pragma unroll
      for (int kc = 0; kc < 8; ++kc) {
        v8s af[4];
#pragma unroll
        for (int mt = 0; mt < 4; ++mt) af[mt] = *(const v8s*)(hrow[mt] + kc*32 + ak);
#pragma unroll
        for (int gg = 0; gg < 2; ++gg)
#pragma unroll
          for (int mt = 0; mt < 4; ++mt)
            acc[mt][gg] = __builtin_amdgcn_mfma_f32_16x16x32_bf16(af[mt], whh_reg[gg][kc], acc[mt][gg], 0,0,0);
      }
    }

    // ---- partial-gate exchange: slice = kh*4 + gate ----
#pragma unroll
    for (int mt=0; mt<4; ++mt)
#pragma unroll
      for (int gg=0; gg<2; ++gg)
#pragma unroll
        for (int r4=0; r4<4; ++r4) {
          int n = mt*16 + hi*4 + r4;
          glds[((kh*4 + gp*2 + gg)*64 + n)*17 + an] = acc[mt][gg][r4];
        }
    __syncthreads();

    // ---- pointwise: sum both K-half partials + biases ----
#pragma unroll
    for (int k = 0; k < 4; ++k) {
      int n = nb_pw + 16*k;
      float g0 = glds[(0*64+n)*17+u_pw] + glds[(4*64+n)*17+u_pw] + bsum[0];
      float g1 = glds[(1*64+n)*17+u_pw] + glds[(5*64+n)*17+u_pw] + bsum[1];
      float g2 = glds[(2*64+n)*17+u_pw] + glds[(6*64+n)*17+u_pw] + bsum[2];
      float g3 = glds[(3*64+n)*17+u_pw] + glds[(7*64+n)*17+u_pw] + bsum[3];
      float cn = sigm(g1)*creg[k] + sigm(g0)*ftanh(g2);
      creg[k] = cn;
      hlds[n*16 + u_pw] = f2bf(sigm(g3)*ftanh(cn));
    }
    __syncthreads();

    // ---- packed write-through h store (16B/thread, 32B per n per block) ----
    if (tid < 128) {
      int n  = tid >> 1;
      int hb = (tid & 1) << 3;
      u64 a = *(const u64*)&hlds[n*16 + hb];
      u64 b = *(const u64*)&hlds[n*16 + hb + 4];
      store_h16(hbuf + ((size_t)(n*512 + t) << 10) + dir*512 + ug*16 + hb, a, b);
    }
    asm volatile("s_waitcnt vmcnt(0)" ::: "memory");
    if (lane == 0)
      __hip_atomic_fetch_add(cnt, 1u, __ATOMIC_RELAXED, __HIP_MEMORY_SCOPE_AGENT);
  }
}

// ---------------------------------------------------------------------------
// Fused attention step
// ---------------------------------------------------------------------------
__global__ __launch_bounds__(256) void attn_step(
    const float* __restrict__ qbuf, const u16* __restrict__ Uah,
    const u16* __restrict__ hid, const int* __restrict__ seq_len,
    const u16* __restrict__ vaW, const u16* __restrict__ vab,
    u16* __restrict__ catb)
{
  int n = blockIdx.x, tid = threadIdx.x;
  __shared__ float qs[1024];
  __shared__ float vas[1024];
  __shared__ float es[512];
  __shared__ float red[8];
  for (int d=tid; d<1024; d+=256){ qs[d]=qbuf[n*1024+d]; vas[d]=bf2f(vaW[d]); }
  __syncthreads();
  int sl = seq_len[n];
  float vb = bf2f(vab[0]);
  for (int l=tid; l<512; l+=256) {
    const u16* up = Uah + ((size_t)n*512 + l)*1024;
    float a = 0.f;
    for (int d=0; d<1024; d+=8) {
      v8s uv = *(const v8s*)(up + d);
#pragma unroll
      for (int e=0;e<8;++e)
        a = fmaf(ftanh(bf2f((u16)uv[e]) + qs[d+e]), vas[d+e], a);
    }
    float ev = a + vb;
    if (l >= sl) ev += NEG_INF;
    es[l] = ev;
  }
  __syncthreads();
  float m = -3.4e38f;
  for (int l=tid; l<512; l+=256) m = fmaxf(m, es[l]);
#pragma unroll
  for (int off=1; off<64; off<<=1) m = fmaxf(m, __shfl_xor(m, off));
  if ((tid&63)==0) red[tid>>6] = m;
  __syncthreads();
  m = fmaxf(fmaxf(red[0],red[1]), fmaxf(red[2],red[3]));
  float s = 0.f;
  for (int l=tid; l<512; l+=256){ float p = __expf(es[l]-m); es[l]=p; s+=p; }
#pragma unroll
  for (int off=1; off<64; off<<=1) s += __shfl_xor(s, off);
  if ((tid&63)==0) red[4+(tid>>6)] = s;
  __syncthreads();
  float inv = 1.f/(red[4]+red[5]+red[6]+red[7]);
  int d0 = tid*4;
  float c0=0,c1=0,c2=0,c3=0;
  for (int l=0; l<512; ++l) {
    float a = es[l];
    const u16* hp = hid + ((size_t)n*512 + l)*1024 + d0;
    v4s hv = *(const v4s*)hp;
    c0 = fmaf(a, bf2f((u16)hv[0]), c0);
    c1 = fmaf(a, bf2f((u16)hv[1]), c1);
    c2 = fmaf(a, bf2f((u16)hv[2]), c2);
    c3 = fmaf(a, bf2f((u16)hv[3]), c3);
  }
  catb[n*2048 + d0 + 0] = f2bf(c0*inv);
  catb[n*2048 + d0 + 1] = f2bf(c1*inv);
  catb[n*2048 + d0 + 2] = f2bf(c2*inv);
  catb[n*2048 + d0 + 3] = f2bf(c3*inv);
}

__global__ void dec_pw(const float* __restrict__ g, u16* __restrict__ scat,
                       u16* __restrict__ catb, int it)
{
  int idx = blockIdx.x*256 + threadIdx.x;
  int n = idx >> 10, d = idx & 1023;
  float gi = g[(size_t)n*4096 + d];
  float gg = g[(size_t)n*4096 + 2048 + d];
  float go = g[(size_t)n*4096 + 3072 + d];
  float c = sigm(gi)*ftanh(gg);
  float s = sigm(go)*ftanh(c);
  u16 hb = f2bf(s);
  scat[((size_t)n*11 + it)*1024 + d] = hb;
  catb[n*2048 + 1024 + d] = hb;
}

__global__ void fill_sentinel(float* out, int nel){
  int i = blockIdx.x*256 + threadIdx.x;
  if (i < nel) out[i] = 12345.0f;
}

// ---------------------------------------------------------------------------
extern "C" void kernel_launch(void* const* d_in, const int* in_sizes, int n_in,
                              void* d_out, int out_size, void* d_ws, size_t ws_size,
                              hipStream_t stream)
{
  const int* X      = (const int*)d_in[0];
  const int* seqlen = (const int*)d_in[1];
  float* out = (float*)d_out;
  char* ws = (char*)d_ws;

  struct Seg { int idx; int n; };
  static const Seg segs[31] = {
    {2, 4096000},
    {3, 262144},{4,1048576},{5,2048},{6,2048},
    {7, 262144},{8,1048576},{9,2048},{10,2048},
    {11,2097152},{12,1048576},{13,2048},{14,2048},
    {15,2097152},{16,1048576},{17,2048},{18,2048},
    {19,1048576},{20,1024},
    {21,1048576},{22,1024},
    {23,1048576},{24,1024},
    {25,1024},{26,1},
    {27,4194304},{28,4194304},{29,4096},{30,4096},
    {31,10240000},{32,10000},
  };
  const u16* bp[33];
  CvtTab tab;
  size_t aoff = 0;
  for (int i = 0; i < 31; ++i) {
    bp[segs[i].idx] = (const u16*)(ws) + aoff;
    tab.src[i] = (const float*)d_in[segs[i].idx];
    tab.off[i] = (unsigned)aoff;
    tab.n[i]   = (unsigned)segs[i].n;
    aoff += (size_t)((segs[i].n + 7) & ~7);
  }
  tab.total = (unsigned)aoff;
  size_t arena_bytes = ((aoff*2 + 255) & ~(size_t)255);

  const size_t H0_OFF   = arena_bytes;
  const size_t HID_OFF  = H0_OFF   + 67108864;
  const size_t BAR_OFF  = HID_OFF  + 67108864;
  const size_t CATB_OFF = BAR_OFF  + 1024;
  const size_t QBUF_OFF = CATB_OFF + 262144;
  const size_t GDEC_OFF = QBUF_OFF + 262144;
  const size_t SCAT_OFF = GDEC_OFF + 1048576;
  const size_t NEED     = SCAT_OFF + 1441792;   // ~201 MB (ws proven >= 221 MB)

  if (ws_size < NEED) {
    fill_sentinel<<<(out_size+255)/256, 256, 0, stream>>>(out, out_size);
    return;
  }

  u16*      h0   = (u16*)(ws + H0_OFF);
  u16*      Uah  = (u16*)(ws + H0_OFF);   // alias: h0 dead after encoder
  u16*      hid  = (u16*)(ws + HID_OFF);
  unsigned* bar  = (unsigned*)(ws + BAR_OFF);
  u16*      catb = (u16*)(ws + CATB_OFF);
  float*    qbuf = (float*)(ws + QBUF_OFF);
  float*    gdec = (float*)(ws + GDEC_OFF);
  u16*      scat = (u16*)(ws + SCAT_OFF);

  hipMemsetAsync(ws + BAR_OFF, 0, 1024, stream);

  {
    unsigned nth = (unsigned)(aoff / 8);
    cvt_all<<<(nth + 255)/256, 256, 0, stream>>>(tab, (u16*)ws);
  }

  // ---- encoder layer 0 (persistent scan, all weights pinned) ----
  lstm_scan<0><<<64, 256, 0, stream>>>(
      bp[2], X, bp[3], bp[7], bp[4], bp[8],
      bp[5], bp[6], bp[9], bp[10], h0, bar);

  // ---- encoder layer 1 ----
  lstm_scan<1><<<64, 256, 0, stream>>>(
      h0, nullptr, bp[11], bp[15], bp[12], bp[16],
      bp[13], bp[14], bp[17], bp[18], hid, bar + 128);

  // ---- attention precompute ----
  gemm_bf16<<<dim3(256,8), 256, 0, stream>>>(hid, 1024, bp[23], bp[24], nullptr,
      Uah, 1024, 32768, 1024, 1024, GF_OUTBF16);
  gemm_bf16<<<dim3(1,8), 256, 0, stream>>>(hid, 524288, bp[19], bp[20], nullptr,
      catb + 1024, 2048, 64, 1024, 1024, GF_OUTBF16 | GF_TANH);

  // ---- 11 decoder steps ----
  for (int it = 0; it < 11; ++it) {
    gemm_bf16<<<dim3(1,8), 256, 0, stream>>>(catb + 1024, 2048, bp[21], bp[22], nullptr,
        qbuf, 1024, 64, 1024, 1024, 0);
    attn_step<<<64, 256, 0, stream>>>(qbuf, Uah, hid, seqlen, bp[25], bp[26], catb);
    gemm_bf16<<<dim3(1,32), 256, 0, stream>>>(catb, 2048, bp[27], bp[29], bp[30],
        gdec, 4096, 64, 4096, 1024, 0);
    gemm_bf16<<<dim3(1,32), 256, 0, stream>>>(catb + 1024, 2048, bp[28], nullptr, nullptr,
        gdec, 4096, 64, 4096, 1024, GF_ACCUM);
    dec_pw<<<256, 256, 0, stream>>>(gdec, scat, catb, it);
  }

  // ---- classifier (f32 output) ----
  gemm_bf16<<<dim3(6,79), 256, 0, stream>>>(scat, 1024, bp[31], bp[32], nullptr,
      out, 10000, 704, 10000, 1024, 0);
}

// Round 8
// 13116.367 us; speedup vs baseline: 2.1659x; 1.0163x over previous
//
#include <hip/hip_runtime.h>
#include <stdint.h>

#define NEG_INF -100000000.0f

typedef unsigned short u16;
typedef unsigned long long u64;
typedef __attribute__((ext_vector_type(8))) short v8s;
typedef __attribute__((ext_vector_type(4))) short v4s;
typedef __attribute__((ext_vector_type(4))) float v4f;

__device__ __forceinline__ float bf2f(u16 h){ return __uint_as_float(((unsigned)h)<<16); }
__device__ __forceinline__ u16 f2bf(float f){
  unsigned u = __float_as_uint(f);
  u = u + 0x7fffu + ((u>>16)&1u);
  return (u16)(u>>16);
}
__device__ __forceinline__ float sigm(float x){ return 1.0f/(1.0f+__expf(-x)); }
__device__ __forceinline__ float ftanh(float x){
  x = fminf(15.0f, fmaxf(-15.0f, x));
  float e = __expf(2.0f*x);
  return (e-1.0f)/(e+1.0f);
}

// write-through (coherence-point) 16B h store; consumer loads are PLAIN
__device__ __forceinline__ void store_h16(u16* p, u64 a, u64 b){
  __hip_atomic_store((u64*)p,     a, __ATOMIC_RELAXED, __HIP_MEMORY_SCOPE_AGENT);
  __hip_atomic_store((u64*)(p+4), b, __ATOMIC_RELAXED, __HIP_MEMORY_SCOPE_AGENT);
}

// ---------------------------------------------------------------------------
// Fused f32 -> bf16 arena conversion
// ---------------------------------------------------------------------------
struct CvtTab {
  const float* src[31];
  unsigned off[31];
  unsigned n[31];
  unsigned total;
};

__global__ __launch_bounds__(256) void cvt_all(CvtTab tab, u16* __restrict__ arena){
  unsigned e0 = (blockIdx.x*256u + threadIdx.x)*8u;
  if (e0 >= tab.total) return;
  int s = 0;
#pragma unroll 1
  for (int i = 1; i < 31; ++i) if (e0 >= tab.off[i]) s = i;
  unsigned rel = e0 - tab.off[s];
  const float* sp = tab.src[s] + rel;
  unsigned nn = tab.n[s];
  union { u16 h[8]; v8s v; } o;
  if (rel + 8 <= nn) {
    float4 a = *(const float4*)sp;
    float4 b = *(const float4*)(sp+4);
    o.h[0]=f2bf(a.x); o.h[1]=f2bf(a.y); o.h[2]=f2bf(a.z); o.h[3]=f2bf(a.w);
    o.h[4]=f2bf(b.x); o.h[5]=f2bf(b.y); o.h[6]=f2bf(b.z); o.h[7]=f2bf(b.w);
  } else {
#pragma unroll
    for (int k = 0; k < 8; ++k) o.h[k] = (rel + k < nn) ? f2bf(sp[k]) : (u16)0;
  }
  *(v8s*)(arena + e0) = o.v;
}

// ---------------------------------------------------------------------------
// Generic bf16 GEMM: C[M][N] = A[M][K] @ B[N][K]^T (+bias1+bias2)(+tanh)(+C)
// ---------------------------------------------------------------------------
#define GF_OUTBF16 1
#define GF_TANH    2
#define GF_ACCUM   4

__global__ __launch_bounds__(256) void gemm_bf16(
    const u16* __restrict__ A, long long lda,
    const u16* __restrict__ B,
    const u16* __restrict__ bias1, const u16* __restrict__ bias2,
    void* __restrict__ Cout, long long ldc,
    int M, int Nn, int K, int flags)
{
  __shared__ u16 As[8192];
  __shared__ u16 Bs[8192];
  int tid = threadIdx.x;
  int lane = tid & 63, w = tid >> 6;
  int wm = w >> 1, wn = w & 1;
  int bm = blockIdx.x * 128, bn = blockIdx.y * 128;

  v4f acc[4][4];
#pragma unroll
  for (int i=0;i<4;++i)
#pragma unroll
    for (int j=0;j<4;++j) acc[i][j] = (v4f){0.f,0.f,0.f,0.f};

#pragma unroll 1
  for (int ko = 0; ko < K; ko += 64) {
    __syncthreads();
#pragma unroll
    for (int it = 0; it < 8; ++it) {
      int c = tid + 256*it;
      int half = c >> 10;
      int cc = c & 1023;
      int r = cc >> 3;
      int kcb = cc & 7;
      const u16* src;
      if (half == 0) {
        int row = min(bm + r, M-1);
        src = A + (size_t)row*(size_t)lda + ko + (kcb<<3);
      } else {
        int row = min(bn + r, Nn-1);
        src = B + (size_t)row*(size_t)K + ko + (kcb<<3);
      }
      v8s v = *(const v8s*)src;
      char* base = (char*)(half ? Bs : As);
      *(v8s*)(base + (r<<7) + ((kcb<<4) ^ ((r&7)<<4))) = v;
    }
    __syncthreads();
#pragma unroll
    for (int ks = 0; ks < 2; ++ks) {
      v8s af[4], bfr[4];
#pragma unroll
      for (int mt=0; mt<4; ++mt) {
        int r = wm*64 + mt*16 + (lane & 15);
        int kb = (ks<<6) + ((lane>>4)<<4);
        af[mt] = *(const v8s*)((const char*)As + (r<<7) + (kb ^ ((r&7)<<4)));
      }
#pragma unroll
      for (int nt=0; nt<4; ++nt) {
        int r = wn*64 + nt*16 + (lane & 15);
        int kb = (ks<<6) + ((lane>>4)<<4);
        bfr[nt] = *(const v8s*)((const char*)Bs + (r<<7) + (kb ^ ((r&7)<<4)));
      }
#pragma unroll
      for (int mt=0; mt<4; ++mt)
#pragma unroll
        for (int nt=0; nt<4; ++nt)
          acc[mt][nt] = __builtin_amdgcn_mfma_f32_16x16x32_bf16(af[mt], bfr[nt], acc[mt][nt], 0,0,0);
    }
  }

#pragma unroll
  for (int mt=0; mt<4; ++mt) {
#pragma unroll
    for (int nt=0; nt<4; ++nt) {
      int col = bn + wn*64 + nt*16 + (lane&15);
      if (col >= Nn) continue;
      float b = 0.f;
      if (bias1) b += bf2f(bias1[col]);
      if (bias2) b += bf2f(bias2[col]);
#pragma unroll
      for (int r=0; r<4; ++r) {
        int row = bm + wm*64 + mt*16 + ((lane>>4)<<2) + r;
        if (row >= M) continue;
        float v = acc[mt][nt][r] + b;
        if (flags & GF_ACCUM) v += ((float*)Cout)[(size_t)row*(size_t)ldc + col];
        if (flags & GF_TANH) v = ftanh(v);
        if (flags & GF_OUTBF16) ((u16*)Cout)[(size_t)row*(size_t)ldc + col] = f2bf(v);
        else                    ((float*)Cout)[(size_t)row*(size_t)ldc + col] = v;
      }
    }
  }
}

// ---------------------------------------------------------------------------
// Persistent bidirectional LSTM scan, 128 blocks x 8 units.
// dir = blk>>6, ug = blk&63. Wave w: kh = w>>1 owns a K-half; gp = w&1 owns a
// gate pair. The MFMA N-dim packs 2 gates x 8 units (B row = lane&15 ->
// gate gp*2+(an>>3), unit an&7). ALL weights VGPR-pinned (L1: 64+32 VGPR).
// Sync: contention-free per-block progress words (64B apart). Producer:
// write-through h stores -> vmcnt(0) -> __syncthreads -> ONE relaxed atomic
// STORE of step+1. Consumer: 64 lanes of wave 0 poll the 64 producer words
// of their dir in parallel (relaxed atomic loads + __all). No RMW contention.
// h data: write-through stores, plain consumer loads (each line read only
// after producer's progress word is seen -> never stale in any cache).
// ---------------------------------------------------------------------------
template<int LAYER>
__global__ __launch_bounds__(256, 1) void lstm_scan(
    const u16* __restrict__ xsrc,      // L0: embW ; L1: h0
    const int* __restrict__ Xidx,      // L0 only
    const u16* __restrict__ Wih_f, const u16* __restrict__ Wih_b,
    const u16* __restrict__ Whh_f, const u16* __restrict__ Whh_b,
    const u16* __restrict__ bih_f, const u16* __restrict__ bhh_f,
    const u16* __restrict__ bih_b, const u16* __restrict__ bhh_b,
    u16* __restrict__ hbuf,            // [64][512][1024] layer output
    unsigned* __restrict__ prog)       // 128 x 16 u32 (one 64B line per block)
{
  constexpr int KX  = (LAYER==0) ? 128 : 1024;
  constexpr int NKC = KX/64;                 // x k-chunks per K-half (2 / 16)
  __shared__ float glds[8*64*10];            // [kh*4+gate][n][10] pad->2-way max
  __shared__ u16   hlds[512];                // [n][8u]

  const int tid = threadIdx.x, lane = tid & 63, w = tid >> 6;
  const int kh = w >> 1, gp = w & 1;
  const int dir = blockIdx.x >> 6, ug = blockIdx.x & 63;
  const int an = lane & 15, hi = lane >> 4, ak = hi << 3;
  const u16* Wih = dir ? Wih_b : Wih_f;
  const u16* Whh = dir ? Whh_b : Whh_f;
  unsigned* myprog = prog + (size_t)blockIdx.x*16;
  const unsigned* pollp = prog + (size_t)(dir*64 + lane)*16;

  // B-row (gate, unit) for this lane
  const int brow_g = gp*2 + (an>>3);
  const int brow_u = (ug<<3) + (an&7);

  // ---- weights pinned in VGPRs ----
  v8s wih_reg[NKC];
  {
    const u16* wp = Wih + ((size_t)brow_g*512 + brow_u)*KX + kh*(KX/2);
#pragma unroll
    for (int kc = 0; kc < NKC; ++kc) {
      wih_reg[kc] = *(const v8s*)(wp + kc*32 + ak);
      asm volatile("" : "+v"(wih_reg[kc]));
    }
  }
  v8s whh_reg[8];
  {
    const u16* wp = Whh + ((size_t)brow_g*512 + brow_u)*512 + kh*256;
#pragma unroll
    for (int kc = 0; kc < 8; ++kc) {
      whh_reg[kc] = *(const v8s*)(wp + kc*32 + ak);
      asm volatile("" : "+v"(whh_reg[kc]));
    }
  }

  const int u_pw = tid & 7, nb_pw = tid >> 3;    // n = nb_pw + 32k
  const int uj_pw = (ug<<3) + u_pw;
  float bsum[4];
  {
    const u16* bi = dir ? bih_b : bih_f;
    const u16* bh = dir ? bhh_b : bhh_f;
#pragma unroll
    for (int q = 0; q < 4; ++q)
      bsum[q] = bf2f(bi[q*512 + uj_pw]) + bf2f(bh[q*512 + uj_pw]);
  }
  float creg[2] = {0.f, 0.f};

  for (int step = 0; step < 512; ++step) {
    const int t     = dir ? (511 - step) : step;
    const int tprev = dir ? (t + 1) : (t - 1);

    v4f acc[4];
#pragma unroll
    for (int i=0;i<4;++i) acc[i] = (v4f){0,0,0,0};

    // ---- x-projection (independent of h_prev; overlaps producers) ----
    {
      const u16* xrow[4];
#pragma unroll
      for (int mt = 0; mt < 4; ++mt) {
        if constexpr (LAYER == 0)
          xrow[mt] = xsrc + (size_t)Xidx[(mt*16 + an)*512 + t]*128 + kh*64;
        else
          xrow[mt] = xsrc + ((size_t)((mt*16 + an)*512 + t) << 10) + kh*512;
      }
#pragma unroll
      for (int kc = 0; kc < NKC; ++kc) {
        v8s af[4];
#pragma unroll
        for (int mt = 0; mt < 4; ++mt) af[mt] = *(const v8s*)(xrow[mt] + kc*32 + ak);
#pragma unroll
        for (int mt = 0; mt < 4; ++mt)
          acc[mt] = __builtin_amdgcn_mfma_f32_16x16x32_bf16(af[mt], wih_reg[kc], acc[mt], 0,0,0);
      }
    }

    // ---- wait for previous step's h (parallel poll of 64 producer words) ----
    if (step > 0) {
      if (w == 0) {
        for (;;) {
          unsigned v = __hip_atomic_load(pollp, __ATOMIC_RELAXED, __HIP_MEMORY_SCOPE_AGENT);
          if (__all(v >= (unsigned)step)) break;
          __builtin_amdgcn_s_sleep(1);
        }
      }
      __syncthreads();
      asm volatile("" ::: "memory");

      // ---- recurrent h_prev @ Whh^T : plain pipelined loads, pinned weights ----
      const u16* hrow[4];
#pragma unroll
      for (int mt = 0; mt < 4; ++mt)
        hrow[mt] = hbuf + ((size_t)((mt*16 + an)*512 + tprev) << 10) + dir*512 + kh*256;
#pragma unroll
      for (int kc = 0; kc < 8; ++kc) {
        v8s af[4];
#pragma unroll
        for (int mt = 0; mt < 4; ++mt) af[mt] = *(const v8s*)(hrow[mt] + kc*32 + ak);
#pragma unroll
        for (int mt = 0; mt < 4; ++mt)
          acc[mt] = __builtin_amdgcn_mfma_f32_16x16x32_bf16(af[mt], whh_reg[kc], acc[mt], 0,0,0);
      }
    }

    // ---- partial-gate exchange: slice = kh*4 + gate, row n, unit an&7 ----
#pragma unroll
    for (int mt=0; mt<4; ++mt)
#pragma unroll
      for (int r=0; r<4; ++r) {
        int n = mt*16 + hi*4 + r;
        glds[((kh*4 + brow_g)*64 + n)*10 + (an&7)] = acc[mt][r];
      }
    __syncthreads();

    // ---- pointwise: sum both K-half partials + biases (2 batches/thread) ----
#pragma unroll
    for (int k = 0; k < 2; ++k) {
      int n = nb_pw + 32*k;
      float g0 = glds[(0*64+n)*10+u_pw] + glds[(4*64+n)*10+u_pw] + bsum[0];
      float g1 = glds[(1*64+n)*10+u_pw] + glds[(5*64+n)*10+u_pw] + bsum[1];
      float g2 = glds[(2*64+n)*10+u_pw] + glds[(6*64+n)*10+u_pw] + bsum[2];
      float g3 = glds[(3*64+n)*10+u_pw] + glds[(7*64+n)*10+u_pw] + bsum[3];
      float cn = sigm(g1)*creg[k] + sigm(g0)*ftanh(g2);
      creg[k] = cn;
      hlds[n*8 + u_pw] = f2bf(sigm(g3)*ftanh(cn));
    }
    __syncthreads();

    // ---- packed write-through h store: one 16B store per batch ----
    if (tid < 64) {
      u64 a = *(const u64*)&hlds[tid*8];
      u64 b = *(const u64*)&hlds[tid*8 + 4];
      store_h16(hbuf + ((size_t)(tid*512 + t) << 10) + dir*512 + (ug<<3), a, b);
    }
    asm volatile("s_waitcnt vmcnt(0)" ::: "memory");
    __syncthreads();   // all waves' stores ACKed at coherence point

    if (tid == 0)
      __hip_atomic_store(myprog, (unsigned)(step+1), __ATOMIC_RELAXED, __HIP_MEMORY_SCOPE_AGENT);
  }
}

// ---------------------------------------------------------------------------
// Fused attention step
// ---------------------------------------------------------------------------
__global__ __launch_bounds__(256) void attn_step(
    const float* __restrict__ qbuf, const u16* __restrict__ Uah,
    const u16* __restrict__ hid, const int* __restrict__ seq_len,
    const u16* __restrict__ vaW, const u16* __restrict__ vab,
    u16* __restrict__ catb)
{
  int n = blockIdx.x, tid = threadIdx.x;
  __shared__ float qs[1024];
  __shared__ float vas[1024];
  __shared__ float es[512];
  __shared__ float red[8];
  for (int d=tid; d<1024; d+=256){ qs[d]=qbuf[n*1024+d]; vas[d]=bf2f(vaW[d]); }
  __syncthreads();
  int sl = seq_len[n];
  float vb = bf2f(vab[0]);
  for (int l=tid; l<512; l+=256) {
    const u16* up = Uah + ((size_t)n*512 + l)*1024;
    float a = 0.f;
    for (int d=0; d<1024; d+=8) {
      v8s uv = *(const v8s*)(up + d);
#pragma unroll
      for (int e=0;e<8;++e)
        a = fmaf(ftanh(bf2f((u16)uv[e]) + qs[d+e]), vas[d+e], a);
    }
    float ev = a + vb;
    if (l >= sl) ev += NEG_INF;
    es[l] = ev;
  }
  __syncthreads();
  float m = -3.4e38f;
  for (int l=tid; l<512; l+=256) m = fmaxf(m, es[l]);
#pragma unroll
  for (int off=1; off<64; off<<=1) m = fmaxf(m, __shfl_xor(m, off));
  if ((tid&63)==0) red[tid>>6] = m;
  __syncthreads();
  m = fmaxf(fmaxf(red[0],red[1]), fmaxf(red[2],red[3]));
  float s = 0.f;
  for (int l=tid; l<512; l+=256){ float p = __expf(es[l]-m); es[l]=p; s+=p; }
#pragma unroll
  for (int off=1; off<64; off<<=1) s += __shfl_xor(s, off);
  if ((tid&63)==0) red[4+(tid>>6)] = s;
  __syncthreads();
  float inv = 1.f/(red[4]+red[5]+red[6]+red[7]);
  int d0 = tid*4;
  float c0=0,c1=0,c2=0,c3=0;
  for (int l=0; l<512; ++l) {
    float a = es[l];
    const u16* hp = hid + ((size_t)n*512 + l)*1024 + d0;
    v4s hv = *(const v4s*)hp;
    c0 = fmaf(a, bf2f((u16)hv[0]), c0);
    c1 = fmaf(a, bf2f((u16)hv[1]), c1);
    c2 = fmaf(a, bf2f((u16)hv[2]), c2);
    c3 = fmaf(a, bf2f((u16)hv[3]), c3);
  }
  catb[n*2048 + d0 + 0] = f2bf(c0*inv);
  catb[n*2048 + d0 + 1] = f2bf(c1*inv);
  catb[n*2048 + d0 + 2] = f2bf(c2*inv);
  catb[n*2048 + d0 + 3] = f2bf(c3*inv);
}

__global__ void dec_pw(const float* __restrict__ g, u16* __restrict__ scat,
                       u16* __restrict__ catb, int it)
{
  int idx = blockIdx.x*256 + threadIdx.x;
  int n = idx >> 10, d = idx & 1023;
  float gi = g[(size_t)n*4096 + d];
  float gg = g[(size_t)n*4096 + 2048 + d];
  float go = g[(size_t)n*4096 + 3072 + d];
  float c = sigm(gi)*ftanh(gg);
  float s = sigm(go)*ftanh(c);
  u16 hb = f2bf(s);
  scat[((size_t)n*11 + it)*1024 + d] = hb;
  catb[n*2048 + 1024 + d] = hb;
}

__global__ void fill_sentinel(float* out, int nel){
  int i = blockIdx.x*256 + threadIdx.x;
  if (i < nel) out[i] = 12345.0f;
}

// ---------------------------------------------------------------------------
extern "C" void kernel_launch(void* const* d_in, const int* in_sizes, int n_in,
                              void* d_out, int out_size, void* d_ws, size_t ws_size,
                              hipStream_t stream)
{
  const int* X      = (const int*)d_in[0];
  const int* seqlen = (const int*)d_in[1];
  float* out = (float*)d_out;
  char* ws = (char*)d_ws;

  struct Seg { int idx; int n; };
  static const Seg segs[31] = {
    {2, 4096000},
    {3, 262144},{4,1048576},{5,2048},{6,2048},
    {7, 262144},{8,1048576},{9,2048},{10,2048},
    {11,2097152},{12,1048576},{13,2048},{14,2048},
    {15,2097152},{16,1048576},{17,2048},{18,2048},
    {19,1048576},{20,1024},
    {21,1048576},{22,1024},
    {23,1048576},{24,1024},
    {25,1024},{26,1},
    {27,4194304},{28,4194304},{29,4096},{30,4096},
    {31,10240000},{32,10000},
  };
  const u16* bp[33];
  CvtTab tab;
  size_t aoff = 0;
  for (int i = 0; i < 31; ++i) {
    bp[segs[i].idx] = (const u16*)(ws) + aoff;
    tab.src[i] = (const float*)d_in[segs[i].idx];
    tab.off[i] = (unsigned)aoff;
    tab.n[i]   = (unsigned)segs[i].n;
    aoff += (size_t)((segs[i].n + 7) & ~7);
  }
  tab.total = (unsigned)aoff;
  size_t arena_bytes = ((aoff*2 + 255) & ~(size_t)255);

  const size_t H0_OFF   = arena_bytes;
  const size_t HID_OFF  = H0_OFF   + 67108864;
  const size_t BAR_OFF  = HID_OFF  + 67108864;   // 16 KB progress words
  const size_t CATB_OFF = BAR_OFF  + 16384;
  const size_t QBUF_OFF = CATB_OFF + 262144;
  const size_t GDEC_OFF = QBUF_OFF + 262144;
  const size_t SCAT_OFF = GDEC_OFF + 1048576;
  const size_t NEED     = SCAT_OFF + 1441792;

  if (ws_size < NEED) {
    fill_sentinel<<<(out_size+255)/256, 256, 0, stream>>>(out, out_size);
    return;
  }

  u16*      h0   = (u16*)(ws + H0_OFF);
  u16*      Uah  = (u16*)(ws + H0_OFF);   // alias: h0 dead after encoder
  u16*      hid  = (u16*)(ws + HID_OFF);
  unsigned* bar  = (unsigned*)(ws + BAR_OFF);
  u16*      catb = (u16*)(ws + CATB_OFF);
  float*    qbuf = (float*)(ws + QBUF_OFF);
  float*    gdec = (float*)(ws + GDEC_OFF);
  u16*      scat = (u16*)(ws + SCAT_OFF);

  hipMemsetAsync(ws + BAR_OFF, 0, 16384, stream);

  {
    unsigned nth = (unsigned)(aoff / 8);
    cvt_all<<<(nth + 255)/256, 256, 0, stream>>>(tab, (u16*)ws);
  }

  // ---- encoder layer 0 (persistent scan) ----
  lstm_scan<0><<<128, 256, 0, stream>>>(
      bp[2], X, bp[3], bp[7], bp[4], bp[8],
      bp[5], bp[6], bp[9], bp[10], h0, bar);

  // ---- encoder layer 1 (separate progress region) ----
  lstm_scan<1><<<128, 256, 0, stream>>>(
      h0, nullptr, bp[11], bp[15], bp[12], bp[16],
      bp[13], bp[14], bp[17], bp[18], hid, bar + 2048);

  // ---- attention precompute ----
  gemm_bf16<<<dim3(256,8), 256, 0, stream>>>(hid, 1024, bp[23], bp[24], nullptr,
      Uah, 1024, 32768, 1024, 1024, GF_OUTBF16);
  gemm_bf16<<<dim3(1,8), 256, 0, stream>>>(hid, 524288, bp[19], bp[20], nullptr,
      catb + 1024, 2048, 64, 1024, 1024, GF_OUTBF16 | GF_TANH);

  // ---- 11 decoder steps ----
  for (int it = 0; it < 11; ++it) {
    gemm_bf16<<<dim3(1,8), 256, 0, stream>>>(catb + 1024, 2048, bp[21], bp[22], nullptr,
        qbuf, 1024, 64, 1024, 1024, 0);
    attn_step<<<64, 256, 0, stream>>>(qbuf, Uah, hid, seqlen, bp[25], bp[26], catb);
    gemm_bf16<<<dim3(1,32), 256, 0, stream>>>(catb, 2048, bp[27], bp[29], bp[30],
        gdec, 4096, 64, 4096, 1024, 0);
    gemm_bf16<<<dim3(1,32), 256, 0, stream>>>(catb + 1024, 2048, bp[28], nullptr, nullptr,
        gdec, 4096, 64, 4096, 1024, GF_ACCUM);
    dec_pw<<<256, 256, 0, stream>>>(gdec, scat, catb, it);
  }

  // ---- classifier (f32 output) ----
  gemm_bf16<<<dim3(6,79), 256, 0, stream>>>(scat, 1024, bp[31], bp[32], nullptr,
      out, 10000, 704, 10000, 1024, 0);
}

// Round 9
// 9850.005 us; speedup vs baseline: 2.8842x; 1.3316x over previous
//
#include <hip/hip_runtime.h>
#include <stdint.h>

#define NEG_INF -100000000.0f

typedef unsigned short u16;
typedef unsigned long long u64;
typedef __attribute__((ext_vector_type(8))) short v8s;
typedef __attribute__((ext_vector_type(4))) short v4s;
typedef __attribute__((ext_vector_type(4))) float v4f;

__device__ __forceinline__ float bf2f(u16 h){ return __uint_as_float(((unsigned)h)<<16); }
__device__ __forceinline__ u16 f2bf(float f){
  unsigned u = __float_as_uint(f);
  u = u + 0x7fffu + ((u>>16)&1u);
  return (u16)(u>>16);
}
__device__ __forceinline__ float sigm(float x){ return 1.0f/(1.0f+__expf(-x)); }
__device__ __forceinline__ float ftanh(float x){
  x = fminf(15.0f, fmaxf(-15.0f, x));
  float e = __expf(2.0f*x);
  return (e-1.0f)/(e+1.0f);
}

// write-through (coherence-point) 16B h store; consumer loads are PLAIN
__device__ __forceinline__ void store_h16(u16* p, u64 a, u64 b){
  __hip_atomic_store((u64*)p,     a, __ATOMIC_RELAXED, __HIP_MEMORY_SCOPE_AGENT);
  __hip_atomic_store((u64*)(p+4), b, __ATOMIC_RELAXED, __HIP_MEMORY_SCOPE_AGENT);
}

// ---------------------------------------------------------------------------
// Fused f32 -> bf16 arena conversion
// ---------------------------------------------------------------------------
struct CvtTab {
  const float* src[31];
  unsigned off[31];
  unsigned n[31];
  unsigned total;
};

__global__ __launch_bounds__(256) void cvt_all(CvtTab tab, u16* __restrict__ arena){
  unsigned e0 = (blockIdx.x*256u + threadIdx.x)*8u;
  if (e0 >= tab.total) return;
  int s = 0;
#pragma unroll 1
  for (int i = 1; i < 31; ++i) if (e0 >= tab.off[i]) s = i;
  unsigned rel = e0 - tab.off[s];
  const float* sp = tab.src[s] + rel;
  unsigned nn = tab.n[s];
  union { u16 h[8]; v8s v; } o;
  if (rel + 8 <= nn) {
    float4 a = *(const float4*)sp;
    float4 b = *(const float4*)(sp+4);
    o.h[0]=f2bf(a.x); o.h[1]=f2bf(a.y); o.h[2]=f2bf(a.z); o.h[3]=f2bf(a.w);
    o.h[4]=f2bf(b.x); o.h[5]=f2bf(b.y); o.h[6]=f2bf(b.z); o.h[7]=f2bf(b.w);
  } else {
#pragma unroll
    for (int k = 0; k < 8; ++k) o.h[k] = (rel + k < nn) ? f2bf(sp[k]) : (u16)0;
  }
  *(v8s*)(arena + e0) = o.v;
}

// ---------------------------------------------------------------------------
// Generic bf16 GEMM: C[M][N] = A[M][K] @ B[N][K]^T (+bias1+bias2)(+tanh)(+C)
// ---------------------------------------------------------------------------
#define GF_OUTBF16 1
#define GF_TANH    2
#define GF_ACCUM   4

__global__ __launch_bounds__(256) void gemm_bf16(
    const u16* __restrict__ A, long long lda,
    const u16* __restrict__ B,
    const u16* __restrict__ bias1, const u16* __restrict__ bias2,
    void* __restrict__ Cout, long long ldc,
    int M, int Nn, int K, int flags)
{
  __shared__ u16 As[8192];
  __shared__ u16 Bs[8192];
  int tid = threadIdx.x;
  int lane = tid & 63, w = tid >> 6;
  int wm = w >> 1, wn = w & 1;
  int bm = blockIdx.x * 128, bn = blockIdx.y * 128;

  v4f acc[4][4];
#pragma unroll
  for (int i=0;i<4;++i)
#pragma unroll
    for (int j=0;j<4;++j) acc[i][j] = (v4f){0.f,0.f,0.f,0.f};

#pragma unroll 1
  for (int ko = 0; ko < K; ko += 64) {
    __syncthreads();
#pragma unroll
    for (int it = 0; it < 8; ++it) {
      int c = tid + 256*it;
      int half = c >> 10;
      int cc = c & 1023;
      int r = cc >> 3;
      int kcb = cc & 7;
      const u16* src;
      if (half == 0) {
        int row = min(bm + r, M-1);
        src = A + (size_t)row*(size_t)lda + ko + (kcb<<3);
      } else {
        int row = min(bn + r, Nn-1);
        src = B + (size_t)row*(size_t)K + ko + (kcb<<3);
      }
      v8s v = *(const v8s*)src;
      char* base = (char*)(half ? Bs : As);
      *(v8s*)(base + (r<<7) + ((kcb<<4) ^ ((r&7)<<4))) = v;
    }
    __syncthreads();
#pragma unroll
    for (int ks = 0; ks < 2; ++ks) {
      v8s af[4], bfr[4];
#pragma unroll
      for (int mt=0; mt<4; ++mt) {
        int r = wm*64 + mt*16 + (lane & 15);
        int kb = (ks<<6) + ((lane>>4)<<4);
        af[mt] = *(const v8s*)((const char*)As + (r<<7) + (kb ^ ((r&7)<<4)));
      }
#pragma unroll
      for (int nt=0; nt<4; ++nt) {
        int r = wn*64 + nt*16 + (lane & 15);
        int kb = (ks<<6) + ((lane>>4)<<4);
        bfr[nt] = *(const v8s*)((const char*)Bs + (r<<7) + (kb ^ ((r&7)<<4)));
      }
#pragma unroll
      for (int mt=0; mt<4; ++mt)
#pragma unroll
        for (int nt=0; nt<4; ++nt)
          acc[mt][nt] = __builtin_amdgcn_mfma_f32_16x16x32_bf16(af[mt], bfr[nt], acc[mt][nt], 0,0,0);
    }
  }

#pragma unroll
  for (int mt=0; mt<4; ++mt) {
#pragma unroll
    for (int nt=0; nt<4; ++nt) {
      int col = bn + wn*64 + nt*16 + (lane&15);
      if (col >= Nn) continue;
      float b = 0.f;
      if (bias1) b += bf2f(bias1[col]);
      if (bias2) b += bf2f(bias2[col]);
#pragma unroll
      for (int r=0; r<4; ++r) {
        int row = bm + wm*64 + mt*16 + ((lane>>4)<<2) + r;
        if (row >= M) continue;
        float v = acc[mt][nt][r] + b;
        if (flags & GF_ACCUM) v += ((float*)Cout)[(size_t)row*(size_t)ldc + col];
        if (flags & GF_TANH) v = ftanh(v);
        if (flags & GF_OUTBF16) ((u16*)Cout)[(size_t)row*(size_t)ldc + col] = f2bf(v);
        else                    ((float*)Cout)[(size_t)row*(size_t)ldc + col] = v;
      }
    }
  }
}

// ---------------------------------------------------------------------------
// Persistent bidirectional LSTM scan.
// 128 blocks = dir(2) x bg(2: 32 batches) x ug(32: 16 units). The 4 (dir,bg)
// groups are INDEPENDENT scans of 32 blocks each (batch-split: a block only
// reads/writes its own 32 batches).
// Waves: kh = w>>1 owns a K-half, gp = w&1 owns a gate pair. MFMA N-dim packs
// 2 gates x 8 units (nt selects unit octet); M-dim = 2 x 16 batches.
// ALL weights VGPR-pinned (L1: 128+64 VGPR/lane).
// Agent-scope (coherent) ops are minimized per wave:
//  - h store: 32 lines/block spread 8 per wave -> short vmcnt(0) drain
//  - progress: one u32 relaxed store per block into a packed 2-line group
//    array; consumer polls 2 lines with 16 lanes (atomic loads serialize per
//    line per wave -> keep line count tiny; this was rounds 5-8's 12us/step)
// h data: write-through stores, plain consumer loads (each line written once,
// read only after producer's progress word is seen -> never stale).
// ---------------------------------------------------------------------------
template<int LAYER>
__global__ __launch_bounds__(256, 1) void lstm_scan(
    const u16* __restrict__ xsrc,      // L0: embW ; L1: h0
    const int* __restrict__ Xidx,      // L0 only
    const u16* __restrict__ Wih_f, const u16* __restrict__ Wih_b,
    const u16* __restrict__ Whh_f, const u16* __restrict__ Whh_b,
    const u16* __restrict__ bih_f, const u16* __restrict__ bhh_f,
    const u16* __restrict__ bih_b, const u16* __restrict__ bhh_b,
    u16* __restrict__ hbuf,            // [64][512][1024] layer output
    unsigned* __restrict__ prog)       // 4 groups x 32 u32 (2 lines each)
{
  constexpr int KX  = (LAYER==0) ? 128 : 1024;
  constexpr int NKC = KX/64;                 // x k-chunks per K-half (2 / 16)
  __shared__ float glds[8*32*18];            // [kh*4+gate][n(32)][u(16)+2pad]
  __shared__ u16   hlds[1024];               // [n(32)][u(16)]

  const int tid = threadIdx.x, lane = tid & 63, w = tid >> 6;
  const int kh = w >> 1, gp = w & 1;
  const int dir = blockIdx.x >> 6, bg = (blockIdx.x >> 5) & 1, ug = blockIdx.x & 31;
  const int an = lane & 15, hi = lane >> 4, ak = hi << 3;
  const u16* Wih = dir ? Wih_b : Wih_f;
  const u16* Whh = dir ? Whh_b : Whh_f;
  const int gid = dir*2 + bg;
  unsigned* gprog = prog + gid*32;           // 32 u32 = 128B = 2 lines

  const int g = 2*gp + (an>>3);              // gate for this lane's B-col

  // ---- weights pinned in VGPRs ----
  v8s wih_reg[2][NKC];
#pragma unroll
  for (int nt = 0; nt < 2; ++nt) {
    const u16* wp = Wih + ((size_t)g*512 + ug*16 + nt*8 + (an&7))*KX + kh*(KX/2);
#pragma unroll
    for (int kc = 0; kc < NKC; ++kc) {
      wih_reg[nt][kc] = *(const v8s*)(wp + kc*32 + ak);
      asm volatile("" : "+v"(wih_reg[nt][kc]));
    }
  }
  v8s whh_reg[2][8];
#pragma unroll
  for (int nt = 0; nt < 2; ++nt) {
    const u16* wp = Whh + ((size_t)g*512 + ug*16 + nt*8 + (an&7))*512 + kh*256;
#pragma unroll
    for (int kc = 0; kc < 8; ++kc) {
      whh_reg[nt][kc] = *(const v8s*)(wp + kc*32 + ak);
      asm volatile("" : "+v"(whh_reg[nt][kc]));
    }
  }

  const int u_pw = tid & 15, n2 = tid >> 4;  // pointwise: unit u_pw, n = k*16+n2
  const int uj_pw = ug*16 + u_pw;
  float bsum[4];
  {
    const u16* bi = dir ? bih_b : bih_f;
    const u16* bh = dir ? bhh_b : bhh_f;
#pragma unroll
    for (int q = 0; q < 4; ++q)
      bsum[q] = bf2f(bi[q*512 + uj_pw]) + bf2f(bh[q*512 + uj_pw]);
  }
  float creg[2] = {0.f, 0.f};

  for (int step = 0; step < 512; ++step) {
    const int t     = dir ? (511 - step) : step;
    const int tprev = dir ? (t + 1) : (t - 1);

    v4f acc[2][2];
#pragma unroll
    for (int i=0;i<2;++i){ acc[i][0]=(v4f){0,0,0,0}; acc[i][1]=(v4f){0,0,0,0}; }

    // ---- x-projection (only this block's 32 batches; overlaps producers) ----
    {
      const u16* xrow[2];
#pragma unroll
      for (int mt = 0; mt < 2; ++mt) {
        int ng = bg*32 + mt*16 + an;
        if constexpr (LAYER == 0)
          xrow[mt] = xsrc + (size_t)Xidx[ng*512 + t]*128 + kh*64;
        else
          xrow[mt] = xsrc + ((size_t)(ng*512 + t) << 10) + kh*512;
      }
#pragma unroll
      for (int kc = 0; kc < NKC; ++kc) {
        v8s af[2];
#pragma unroll
        for (int mt = 0; mt < 2; ++mt) af[mt] = *(const v8s*)(xrow[mt] + kc*32 + ak);
#pragma unroll
        for (int nt = 0; nt < 2; ++nt)
#pragma unroll
          for (int mt = 0; mt < 2; ++mt)
            acc[mt][nt] = __builtin_amdgcn_mfma_f32_16x16x32_bf16(af[mt], wih_reg[nt][kc], acc[mt][nt], 0,0,0);
      }
    }

    // ---- wait for previous step's h (poll 2 packed lines, 16 lanes) ----
    if (step > 0) {
      if (w == 0) {
        const u64* pl = (const u64*)gprog;
        for (;;) {
          u64 v = ~0ull;
          if (lane < 16)
            v = __hip_atomic_load(pl + lane, __ATOMIC_RELAXED, __HIP_MEMORY_SCOPE_AGENT);
          bool ok = ((unsigned)v >= (unsigned)step) && ((unsigned)(v>>32) >= (unsigned)step);
          if (__all(ok)) break;
          __builtin_amdgcn_s_sleep(1);
        }
      }
      __syncthreads();
      asm volatile("" ::: "memory");

      // ---- recurrent h_prev @ Whh^T : plain pipelined loads, pinned weights ----
      const u16* hrow[2];
#pragma unroll
      for (int mt = 0; mt < 2; ++mt) {
        int ng = bg*32 + mt*16 + an;
        hrow[mt] = hbuf + ((size_t)(ng*512 + tprev) << 10) + dir*512 + kh*256;
      }
#pragma unroll
      for (int kc = 0; kc < 8; ++kc) {
        v8s af[2];
#pragma unroll
        for (int mt = 0; mt < 2; ++mt) af[mt] = *(const v8s*)(hrow[mt] + kc*32 + ak);
#pragma unroll
        for (int nt = 0; nt < 2; ++nt)
#pragma unroll
          for (int mt = 0; mt < 2; ++mt)
            acc[mt][nt] = __builtin_amdgcn_mfma_f32_16x16x32_bf16(af[mt], whh_reg[nt][kc], acc[mt][nt], 0,0,0);
      }
    }

    // ---- partial-gate exchange: slice = kh*4+gate, row n(32), col u(16) ----
#pragma unroll
    for (int mt=0; mt<2; ++mt)
#pragma unroll
      for (int nt=0; nt<2; ++nt)
#pragma unroll
        for (int r=0; r<4; ++r) {
          int n = mt*16 + hi*4 + r;
          int u = nt*8 + (an&7);
          glds[((kh*4 + g)*32 + n)*18 + u] = acc[mt][nt][r];
        }
    __syncthreads();

    // ---- pointwise: sum both K-half partials + biases (2 batches/thread) ----
#pragma unroll
    for (int k = 0; k < 2; ++k) {
      int n = k*16 + n2;
      float g0 = glds[(0*32+n)*18+u_pw] + glds[(4*32+n)*18+u_pw] + bsum[0];
      float g1 = glds[(1*32+n)*18+u_pw] + glds[(5*32+n)*18+u_pw] + bsum[1];
      float g2 = glds[(2*32+n)*18+u_pw] + glds[(6*32+n)*18+u_pw] + bsum[2];
      float g3 = glds[(3*32+n)*18+u_pw] + glds[(7*32+n)*18+u_pw] + bsum[3];
      float cn = sigm(g1)*creg[k] + sigm(g0)*ftanh(g2);
      creg[k] = cn;
      hlds[n*16 + u_pw] = f2bf(sigm(g3)*ftanh(cn));
    }
    __syncthreads();

    // ---- packed write-through h store: 8 lines per wave (4 waves) ----
    if (lane < 16) {
      int n    = w*8 + (lane>>1);
      int half = lane & 1;
      u64 a = *(const u64*)&hlds[n*16 + half*8];
      u64 b = *(const u64*)&hlds[n*16 + half*8 + 4];
      store_h16(hbuf + ((size_t)((bg*32+n)*512 + t) << 10) + dir*512 + ug*16 + half*8, a, b);
    }
    asm volatile("s_waitcnt vmcnt(0)" ::: "memory");
    __syncthreads();   // all waves' stores ACKed at coherence point

    if (tid == 0)
      __hip_atomic_store(gprog + ug, (unsigned)(step+1), __ATOMIC_RELAXED, __HIP_MEMORY_SCOPE_AGENT);
  }
}

// ---------------------------------------------------------------------------
// Fused attention step
// ---------------------------------------------------------------------------
__global__ __launch_bounds__(256) void attn_step(
    const float* __restrict__ qbuf, const u16* __restrict__ Uah,
    const u16* __restrict__ hid, const int* __restrict__ seq_len,
    const u16* __restrict__ vaW, const u16* __restrict__ vab,
    u16* __restrict__ catb)
{
  int n = blockIdx.x, tid = threadIdx.x;
  __shared__ float qs[1024];
  __shared__ float vas[1024];
  __shared__ float es[512];
  __shared__ float red[8];
  for (int d=tid; d<1024; d+=256){ qs[d]=qbuf[n*1024+d]; vas[d]=bf2f(vaW[d]); }
  __syncthreads();
  int sl = seq_len[n];
  float vb = bf2f(vab[0]);
  for (int l=tid; l<512; l+=256) {
    const u16* up = Uah + ((size_t)n*512 + l)*1024;
    float a = 0.f;
    for (int d=0; d<1024; d+=8) {
      v8s uv = *(const v8s*)(up + d);
#pragma unroll
      for (int e=0;e<8;++e)
        a = fmaf(ftanh(bf2f((u16)uv[e]) + qs[d+e]), vas[d+e], a);
    }
    float ev = a + vb;
    if (l >= sl) ev += NEG_INF;
    es[l] = ev;
  }
  __syncthreads();
  float m = -3.4e38f;
  for (int l=tid; l<512; l+=256) m = fmaxf(m, es[l]);
#pragma unroll
  for (int off=1; off<64; off<<=1) m = fmaxf(m, __shfl_xor(m, off));
  if ((tid&63)==0) red[tid>>6] = m;
  __syncthreads();
  m = fmaxf(fmaxf(red[0],red[1]), fmaxf(red[2],red[3]));
  float s = 0.f;
  for (int l=tid; l<512; l+=256){ float p = __expf(es[l]-m); es[l]=p; s+=p; }
#pragma unroll
  for (int off=1; off<64; off<<=1) s += __shfl_xor(s, off);
  if ((tid&63)==0) red[4+(tid>>6)] = s;
  __syncthreads();
  float inv = 1.f/(red[4]+red[5]+red[6]+red[7]);
  int d0 = tid*4;
  float c0=0,c1=0,c2=0,c3=0;
  for (int l=0; l<512; ++l) {
    float a = es[l];
    const u16* hp = hid + ((size_t)n*512 + l)*1024 + d0;
    v4s hv = *(const v4s*)hp;
    c0 = fmaf(a, bf2f((u16)hv[0]), c0);
    c1 = fmaf(a, bf2f((u16)hv[1]), c1);
    c2 = fmaf(a, bf2f((u16)hv[2]), c2);
    c3 = fmaf(a, bf2f((u16)hv[3]), c3);
  }
  catb[n*2048 + d0 + 0] = f2bf(c0*inv);
  catb[n*2048 + d0 + 1] = f2bf(c1*inv);
  catb[n*2048 + d0 + 2] = f2bf(c2*inv);
  catb[n*2048 + d0 + 3] = f2bf(c3*inv);
}

__global__ void dec_pw(const float* __restrict__ g, u16* __restrict__ scat,
                       u16* __restrict__ catb, int it)
{
  int idx = blockIdx.x*256 + threadIdx.x;
  int n = idx >> 10, d = idx & 1023;
  float gi = g[(size_t)n*4096 + d];
  float gg = g[(size_t)n*4096 + 2048 + d];
  float go = g[(size_t)n*4096 + 3072 + d];
  float c = sigm(gi)*ftanh(gg);
  float s = sigm(go)*ftanh(c);
  u16 hb = f2bf(s);
  scat[((size_t)n*11 + it)*1024 + d] = hb;
  catb[n*2048 + 1024 + d] = hb;
}

__global__ void fill_sentinel(float* out, int nel){
  int i = blockIdx.x*256 + threadIdx.x;
  if (i < nel) out[i] = 12345.0f;
}

// ---------------------------------------------------------------------------
extern "C" void kernel_launch(void* const* d_in, const int* in_sizes, int n_in,
                              void* d_out, int out_size, void* d_ws, size_t ws_size,
                              hipStream_t stream)
{
  const int* X      = (const int*)d_in[0];
  const int* seqlen = (const int*)d_in[1];
  float* out = (float*)d_out;
  char* ws = (char*)d_ws;

  struct Seg { int idx; int n; };
  static const Seg segs[31] = {
    {2, 4096000},
    {3, 262144},{4,1048576},{5,2048},{6,2048},
    {7, 262144},{8,1048576},{9,2048},{10,2048},
    {11,2097152},{12,1048576},{13,2048},{14,2048},
    {15,2097152},{16,1048576},{17,2048},{18,2048},
    {19,1048576},{20,1024},
    {21,1048576},{22,1024},
    {23,1048576},{24,1024},
    {25,1024},{26,1},
    {27,4194304},{28,4194304},{29,4096},{30,4096},
    {31,10240000},{32,10000},
  };
  const u16* bp[33];
  CvtTab tab;
  size_t aoff = 0;
  for (int i = 0; i < 31; ++i) {
    bp[segs[i].idx] = (const u16*)(ws) + aoff;
    tab.src[i] = (const float*)d_in[segs[i].idx];
    tab.off[i] = (unsigned)aoff;
    tab.n[i]   = (unsigned)segs[i].n;
    aoff += (size_t)((segs[i].n + 7) & ~7);
  }
  tab.total = (unsigned)aoff;
  size_t arena_bytes = ((aoff*2 + 255) & ~(size_t)255);

  const size_t H0_OFF   = arena_bytes;
  const size_t HID_OFF  = H0_OFF   + 67108864;
  const size_t BAR_OFF  = HID_OFF  + 67108864;   // 16 KB progress words
  const size_t CATB_OFF = BAR_OFF  + 16384;
  const size_t QBUF_OFF = CATB_OFF + 262144;
  const size_t GDEC_OFF = QBUF_OFF + 262144;
  const size_t SCAT_OFF = GDEC_OFF + 1048576;
  const size_t NEED     = SCAT_OFF + 1441792;

  if (ws_size < NEED) {
    fill_sentinel<<<(out_size+255)/256, 256, 0, stream>>>(out, out_size);
    return;
  }

  u16*      h0   = (u16*)(ws + H0_OFF);
  u16*      Uah  = (u16*)(ws + H0_OFF);   // alias: h0 dead after encoder
  u16*      hid  = (u16*)(ws + HID_OFF);
  unsigned* bar  = (unsigned*)(ws + BAR_OFF);
  u16*      catb = (u16*)(ws + CATB_OFF);
  float*    qbuf = (float*)(ws + QBUF_OFF);
  float*    gdec = (float*)(ws + GDEC_OFF);
  u16*      scat = (u16*)(ws + SCAT_OFF);

  hipMemsetAsync(ws + BAR_OFF, 0, 16384, stream);

  {
    unsigned nth = (unsigned)(aoff / 8);
    cvt_all<<<(nth + 255)/256, 256, 0, stream>>>(tab, (u16*)ws);
  }

  // ---- encoder layer 0 (persistent scan) ----
  lstm_scan<0><<<128, 256, 0, stream>>>(
      bp[2], X, bp[3], bp[7], bp[4], bp[8],
      bp[5], bp[6], bp[9], bp[10], h0, bar);

  // ---- encoder layer 1 (separate progress region, +4KB) ----
  lstm_scan<1><<<128, 256, 0, stream>>>(
      h0, nullptr, bp[11], bp[15], bp[12], bp[16],
      bp[13], bp[14], bp[17], bp[18], hid, bar + 1024);

  // ---- attention precompute ----
  gemm_bf16<<<dim3(256,8), 256, 0, stream>>>(hid, 1024, bp[23], bp[24], nullptr,
      Uah, 1024, 32768, 1024, 1024, GF_OUTBF16);
  gemm_bf16<<<dim3(1,8), 256, 0, stream>>>(hid, 524288, bp[19], bp[20], nullptr,
      catb + 1024, 2048, 64, 1024, 1024, GF_OUTBF16 | GF_TANH);

  // ---- 11 decoder steps ----
  for (int it = 0; it < 11; ++it) {
    gemm_bf16<<<dim3(1,8), 256, 0, stream>>>(catb + 1024, 2048, bp[21], bp[22], nullptr,
        qbuf, 1024, 64, 1024, 1024, 0);
    attn_step<<<64, 256, 0, stream>>>(qbuf, Uah, hid, seqlen, bp[25], bp[26], catb);
    gemm_bf16<<<dim3(1,32), 256, 0, stream>>>(catb, 2048, bp[27], bp[29], bp[30],
        gdec, 4096, 64, 4096, 1024, 0);
    gemm_bf16<<<dim3(1,32), 256, 0, stream>>>(catb + 1024, 2048, bp[28], nullptr, nullptr,
        gdec, 4096, 64, 4096, 1024, GF_ACCUM);
    dec_pw<<<256, 256, 0, stream>>>(gdec, scat, catb, it);
  }

  // ---- classifier (f32 output) ----
  gemm_bf16<<<dim3(6,79), 256, 0, stream>>>(scat, 1024, bp[31], bp[32], nullptr,
      out, 10000, 704, 10000, 1024, 0);
}

// Round 10
// 9742.262 us; speedup vs baseline: 2.9161x; 1.0111x over previous
//
#include <hip/hip_runtime.h>
#include <stdint.h>

#define NEG_INF -100000000.0f

typedef unsigned short u16;
typedef unsigned long long u64;
typedef __attribute__((ext_vector_type(8))) short v8s;
typedef __attribute__((ext_vector_type(4))) short v4s;
typedef __attribute__((ext_vector_type(4))) float v4f;

__device__ __forceinline__ float bf2f(u16 h){ return __uint_as_float(((unsigned)h)<<16); }
__device__ __forceinline__ u16 f2bf(float f){
  unsigned u = __float_as_uint(f);
  u = u + 0x7fffu + ((u>>16)&1u);
  return (u16)(u>>16);
}
__device__ __forceinline__ float sigm(float x){ return 1.0f/(1.0f+__expf(-x)); }
__device__ __forceinline__ float ftanh(float x){
  x = fminf(15.0f, fmaxf(-15.0f, x));
  float e = __expf(2.0f*x);
  return (e-1.0f)/(e+1.0f);
}

// write-through (coherence-point) 16B h store; consumer loads are PLAIN
__device__ __forceinline__ void store_h16(u16* p, u64 a, u64 b){
  __hip_atomic_store((u64*)p,     a, __ATOMIC_RELAXED, __HIP_MEMORY_SCOPE_AGENT);
  __hip_atomic_store((u64*)(p+4), b, __ATOMIC_RELAXED, __HIP_MEMORY_SCOPE_AGENT);
}

// ---------------------------------------------------------------------------
// Fused f32 -> bf16 arena conversion
// ---------------------------------------------------------------------------
struct CvtTab {
  const float* src[31];
  unsigned off[31];
  unsigned n[31];
  unsigned total;
};

__global__ __launch_bounds__(256) void cvt_all(CvtTab tab, u16* __restrict__ arena){
  unsigned e0 = (blockIdx.x*256u + threadIdx.x)*8u;
  if (e0 >= tab.total) return;
  int s = 0;
#pragma unroll 1
  for (int i = 1; i < 31; ++i) if (e0 >= tab.off[i]) s = i;
  unsigned rel = e0 - tab.off[s];
  const float* sp = tab.src[s] + rel;
  unsigned nn = tab.n[s];
  union { u16 h[8]; v8s v; } o;
  if (rel + 8 <= nn) {
    float4 a = *(const float4*)sp;
    float4 b = *(const float4*)(sp+4);
    o.h[0]=f2bf(a.x); o.h[1]=f2bf(a.y); o.h[2]=f2bf(a.z); o.h[3]=f2bf(a.w);
    o.h[4]=f2bf(b.x); o.h[5]=f2bf(b.y); o.h[6]=f2bf(b.z); o.h[7]=f2bf(b.w);
  } else {
#pragma unroll
    for (int k = 0; k < 8; ++k) o.h[k] = (rel + k < nn) ? f2bf(sp[k]) : (u16)0;
  }
  *(v8s*)(arena + e0) = o.v;
}

// ---------------------------------------------------------------------------
// Generic bf16 GEMM: C[M][N] = A[M][K] @ B[N][K]^T (+bias1+bias2)(+tanh)(+C)
// ---------------------------------------------------------------------------
#define GF_OUTBF16 1
#define GF_TANH    2
#define GF_ACCUM   4

__global__ __launch_bounds__(256) void gemm_bf16(
    const u16* __restrict__ A, long long lda,
    const u16* __restrict__ B,
    const u16* __restrict__ bias1, const u16* __restrict__ bias2,
    void* __restrict__ Cout, long long ldc,
    int M, int Nn, int K, int flags)
{
  __shared__ u16 As[8192];
  __shared__ u16 Bs[8192];
  int tid = threadIdx.x;
  int lane = tid & 63, w = tid >> 6;
  int wm = w >> 1, wn = w & 1;
  int bm = blockIdx.x * 128, bn = blockIdx.y * 128;

  v4f acc[4][4];
#pragma unroll
  for (int i=0;i<4;++i)
#pragma unroll
    for (int j=0;j<4;++j) acc[i][j] = (v4f){0.f,0.f,0.f,0.f};

#pragma unroll 1
  for (int ko = 0; ko < K; ko += 64) {
    __syncthreads();
#pragma unroll
    for (int it = 0; it < 8; ++it) {
      int c = tid + 256*it;
      int half = c >> 10;
      int cc = c & 1023;
      int r = cc >> 3;
      int kcb = cc & 7;
      const u16* src;
      if (half == 0) {
        int row = min(bm + r, M-1);
        src = A + (size_t)row*(size_t)lda + ko + (kcb<<3);
      } else {
        int row = min(bn + r, Nn-1);
        src = B + (size_t)row*(size_t)K + ko + (kcb<<3);
      }
      v8s v = *(const v8s*)src;
      char* base = (char*)(half ? Bs : As);
      *(v8s*)(base + (r<<7) + ((kcb<<4) ^ ((r&7)<<4))) = v;
    }
    __syncthreads();
#pragma unroll
    for (int ks = 0; ks < 2; ++ks) {
      v8s af[4], bfr[4];
#pragma unroll
      for (int mt=0; mt<4; ++mt) {
        int r = wm*64 + mt*16 + (lane & 15);
        int kb = (ks<<6) + ((lane>>4)<<4);
        af[mt] = *(const v8s*)((const char*)As + (r<<7) + (kb ^ ((r&7)<<4)));
      }
#pragma unroll
      for (int nt=0; nt<4; ++nt) {
        int r = wn*64 + nt*16 + (lane & 15);
        int kb = (ks<<6) + ((lane>>4)<<4);
        bfr[nt] = *(const v8s*)((const char*)Bs + (r<<7) + (kb ^ ((r&7)<<4)));
      }
#pragma unroll
      for (int mt=0; mt<4; ++mt)
#pragma unroll
        for (int nt=0; nt<4; ++nt)
          acc[mt][nt] = __builtin_amdgcn_mfma_f32_16x16x32_bf16(af[mt], bfr[nt], acc[mt][nt], 0,0,0);
    }
  }

#pragma unroll
  for (int mt=0; mt<4; ++mt) {
#pragma unroll
    for (int nt=0; nt<4; ++nt) {
      int col = bn + wn*64 + nt*16 + (lane&15);
      if (col >= Nn) continue;
      float b = 0.f;
      if (bias1) b += bf2f(bias1[col]);
      if (bias2) b += bf2f(bias2[col]);
#pragma unroll
      for (int r=0; r<4; ++r) {
        int row = bm + wm*64 + mt*16 + ((lane>>4)<<2) + r;
        if (row >= M) continue;
        float v = acc[mt][nt][r] + b;
        if (flags & GF_ACCUM) v += ((float*)Cout)[(size_t)row*(size_t)ldc + col];
        if (flags & GF_TANH) v = ftanh(v);
        if (flags & GF_OUTBF16) ((u16*)Cout)[(size_t)row*(size_t)ldc + col] = f2bf(v);
        else                    ((float*)Cout)[(size_t)row*(size_t)ldc + col] = v;
      }
    }
  }
}

// ---------------------------------------------------------------------------
// Persistent bidirectional LSTM scan (round-9 skeleton + pipelined schedule).
// 128 blocks = dir(2) x bg(2: 32 batches) x ug(32: 16 units); 4 independent
// groups of 32 blocks. Waves: kh = w>>1 (K-half), gp = w&1 (gate pair);
// MFMA N packs 2 gates x 8 units. Weights VGPR-pinned.
// Per-step schedule (2 syncthreads):
//   [x(s) already in regs]  poll(per-wave, 2 lines)  ->  issue h loads ->
//   x-MFMA (reg-only, hides h flight) -> h-MFMA -> glds exchange -> SYNC ->
//   pointwise -> hlds (wave-local rows) -> h store (same wave) ->
//   prefetch x(s+1) -> vmcnt(0) [stores & x-loads drain together] -> SYNC ->
//   progress store.
// Coherence: write-through relaxed-atomic h stores (LLC merge), plain
// consumer loads (lines written once, read only after progress seen).
// ---------------------------------------------------------------------------
template<int LAYER>
__global__ __launch_bounds__(256, 1) void lstm_scan(
    const u16* __restrict__ xsrc,      // L0: embW ; L1: h0
    const int* __restrict__ Xidx,      // L0 only
    const u16* __restrict__ Wih_f, const u16* __restrict__ Wih_b,
    const u16* __restrict__ Whh_f, const u16* __restrict__ Whh_b,
    const u16* __restrict__ bih_f, const u16* __restrict__ bhh_f,
    const u16* __restrict__ bih_b, const u16* __restrict__ bhh_b,
    u16* __restrict__ hbuf,            // [64][512][1024] layer output
    unsigned* __restrict__ prog)       // 4 groups x 32 u32 (2 lines each)
{
  constexpr int KX  = (LAYER==0) ? 128 : 1024;
  constexpr int NKC = KX/64;                 // x k-chunks per K-half (2 / 16)
  __shared__ float glds[8*32*18];            // [kh*4+gate][n(32)][u(16)+2pad]
  __shared__ u16   hlds[1024];               // [n(32)][u(16)]

  const int tid = threadIdx.x, lane = tid & 63, w = tid >> 6;
  const int kh = w >> 1, gp = w & 1;
  const int dir = blockIdx.x >> 6, bg = (blockIdx.x >> 5) & 1, ug = blockIdx.x & 31;
  const int an = lane & 15, hi = lane >> 4, ak = hi << 3;
  const u16* Wih = dir ? Wih_b : Wih_f;
  const u16* Whh = dir ? Whh_b : Whh_f;
  const int gid = dir*2 + bg;
  unsigned* gprog = prog + gid*32;           // 32 u32 = 128B = 2 lines

  const int g = 2*gp + (an>>3);              // gate for this lane's B-col

  // ---- weights pinned in VGPRs ----
  v8s wih_reg[2][NKC];
#pragma unroll
  for (int nt = 0; nt < 2; ++nt) {
    const u16* wp = Wih + ((size_t)g*512 + ug*16 + nt*8 + (an&7))*KX + kh*(KX/2);
#pragma unroll
    for (int kc = 0; kc < NKC; ++kc) {
      wih_reg[nt][kc] = *(const v8s*)(wp + kc*32 + ak);
      asm volatile("" : "+v"(wih_reg[nt][kc]));
    }
  }
  v8s whh_reg[2][8];
#pragma unroll
  for (int nt = 0; nt < 2; ++nt) {
    const u16* wp = Whh + ((size_t)g*512 + ug*16 + nt*8 + (an&7))*512 + kh*256;
#pragma unroll
    for (int kc = 0; kc < 8; ++kc) {
      whh_reg[nt][kc] = *(const v8s*)(wp + kc*32 + ak);
      asm volatile("" : "+v"(whh_reg[nt][kc]));
    }
  }

  const int u_pw = tid & 15, n2 = tid >> 4;  // pointwise: unit u_pw, rows n2, n2+16
  const int uj_pw = ug*16 + u_pw;
  float bsum[4];
  {
    const u16* bi = dir ? bih_b : bih_f;
    const u16* bh = dir ? bhh_b : bhh_f;
#pragma unroll
    for (int q = 0; q < 4; ++q)
      bsum[q] = bf2f(bi[q*512 + uj_pw]) + bf2f(bh[q*512 + uj_pw]);
  }
  float creg[2] = {0.f, 0.f};

  // ---- x prefetch registers: load step 0 ----
  v8s xreg[2][NKC];
  {
    const int t0 = dir ? 511 : 0;
#pragma unroll
    for (int mt = 0; mt < 2; ++mt) {
      int ng = bg*32 + mt*16 + an;
      const u16* xr;
      if constexpr (LAYER == 0) xr = xsrc + (size_t)Xidx[ng*512 + t0]*128 + kh*64;
      else                      xr = xsrc + ((size_t)(ng*512 + t0) << 10) + kh*512;
#pragma unroll
      for (int kc = 0; kc < NKC; ++kc) xreg[mt][kc] = *(const v8s*)(xr + kc*32 + ak);
    }
  }

  for (int step = 0; step < 512; ++step) {
    const int t     = dir ? (511 - step) : step;
    const int tprev = dir ? (t + 1) : (t - 1);

    v4f acc[2][2];
#pragma unroll
    for (int i=0;i<2;++i){ acc[i][0]=(v4f){0,0,0,0}; acc[i][1]=(v4f){0,0,0,0}; }

    if (step > 0) {
      // ---- per-wave poll (2 packed lines, spin-first) ----
      {
        const u64* pl = (const u64*)gprog;
        int spins = 0;
        for (;;) {
          u64 v = ~0ull;
          if (lane < 16)
            v = __hip_atomic_load(pl + lane, __ATOMIC_RELAXED, __HIP_MEMORY_SCOPE_AGENT);
          bool ok = ((unsigned)v >= (unsigned)step) && ((unsigned)(v>>32) >= (unsigned)step);
          if (__all(ok)) break;
          if (++spins > 4) __builtin_amdgcn_s_sleep(1);
        }
        asm volatile("" ::: "memory");
      }

      // ---- issue h loads first; x-MFMA (register-only) hides their flight ----
      v8s haf[2][8];
#pragma unroll
      for (int mt = 0; mt < 2; ++mt) {
        int ng = bg*32 + mt*16 + an;
        const u16* hr = hbuf + ((size_t)(ng*512 + tprev) << 10) + dir*512 + kh*256;
#pragma unroll
        for (int kc = 0; kc < 8; ++kc) haf[mt][kc] = *(const v8s*)(hr + kc*32 + ak);
      }
#pragma unroll
      for (int kc = 0; kc < NKC; ++kc)
#pragma unroll
        for (int nt = 0; nt < 2; ++nt)
#pragma unroll
          for (int mt = 0; mt < 2; ++mt)
            acc[mt][nt] = __builtin_amdgcn_mfma_f32_16x16x32_bf16(xreg[mt][kc], wih_reg[nt][kc], acc[mt][nt], 0,0,0);
#pragma unroll
      for (int kc = 0; kc < 8; ++kc)
#pragma unroll
        for (int nt = 0; nt < 2; ++nt)
#pragma unroll
          for (int mt = 0; mt < 2; ++mt)
            acc[mt][nt] = __builtin_amdgcn_mfma_f32_16x16x32_bf16(haf[mt][kc], whh_reg[nt][kc], acc[mt][nt], 0,0,0);
    } else {
#pragma unroll
      for (int kc = 0; kc < NKC; ++kc)
#pragma unroll
        for (int nt = 0; nt < 2; ++nt)
#pragma unroll
          for (int mt = 0; mt < 2; ++mt)
            acc[mt][nt] = __builtin_amdgcn_mfma_f32_16x16x32_bf16(xreg[mt][kc], wih_reg[nt][kc], acc[mt][nt], 0,0,0);
    }

    // ---- partial-gate exchange: slice = kh*4+gate, row n(32), col u(16) ----
#pragma unroll
    for (int mt=0; mt<2; ++mt)
#pragma unroll
      for (int nt=0; nt<2; ++nt)
#pragma unroll
        for (int r=0; r<4; ++r) {
          int n = mt*16 + hi*4 + r;
          int u = nt*8 + (an&7);
          glds[((kh*4 + g)*32 + n)*18 + u] = acc[mt][nt][r];
        }
    __syncthreads();

    // ---- pointwise: sum both K-half partials + biases (rows n2, n2+16) ----
#pragma unroll
    for (int k = 0; k < 2; ++k) {
      int n = k*16 + n2;
      float g0 = glds[(0*32+n)*18+u_pw] + glds[(4*32+n)*18+u_pw] + bsum[0];
      float g1 = glds[(1*32+n)*18+u_pw] + glds[(5*32+n)*18+u_pw] + bsum[1];
      float g2 = glds[(2*32+n)*18+u_pw] + glds[(6*32+n)*18+u_pw] + bsum[2];
      float g3 = glds[(3*32+n)*18+u_pw] + glds[(7*32+n)*18+u_pw] + bsum[3];
      float cn = sigm(g1)*creg[k] + sigm(g0)*ftanh(g2);
      creg[k] = cn;
      hlds[n*16 + u_pw] = f2bf(sigm(g3)*ftanh(cn));
    }
    // rows {4w..4w+3, 16+4w..19+4w} were written by THIS wave -> no block sync;
    // compiler inserts lgkmcnt before the dependent LDS reads below.

    // ---- wave-local packed write-through h store (8 lines per wave) ----
    if (lane < 16) {
      int j = lane >> 1;
      int n = 4*w + (j & 3) + 16*(j >> 2);
      int half = lane & 1;
      u64 a = *(const u64*)&hlds[n*16 + half*8];
      u64 b = *(const u64*)&hlds[n*16 + half*8 + 4];
      store_h16(hbuf + ((size_t)((bg*32+n)*512 + t) << 10) + dir*512 + ug*16 + half*8, a, b);
    }

    // ---- prefetch x for next step (drains together with the stores) ----
    if (step < 511) {
      const int tn = dir ? (t - 1) : (t + 1);
#pragma unroll
      for (int mt = 0; mt < 2; ++mt) {
        int ng = bg*32 + mt*16 + an;
        const u16* xr;
        if constexpr (LAYER == 0) xr = xsrc + (size_t)Xidx[ng*512 + tn]*128 + kh*64;
        else                      xr = xsrc + ((size_t)(ng*512 + tn) << 10) + kh*512;
#pragma unroll
        for (int kc = 0; kc < NKC; ++kc) xreg[mt][kc] = *(const v8s*)(xr + kc*32 + ak);
      }
    }

    asm volatile("s_waitcnt vmcnt(0)" ::: "memory");
    __syncthreads();   // all waves' stores ACKed at coherence point

    if (tid == 0)
      __hip_atomic_store(gprog + ug, (unsigned)(step+1), __ATOMIC_RELAXED, __HIP_MEMORY_SCOPE_AGENT);
  }
}

// ---------------------------------------------------------------------------
// Fused attention step
// ---------------------------------------------------------------------------
__global__ __launch_bounds__(256) void attn_step(
    const float* __restrict__ qbuf, const u16* __restrict__ Uah,
    const u16* __restrict__ hid, const int* __restrict__ seq_len,
    const u16* __restrict__ vaW, const u16* __restrict__ vab,
    u16* __restrict__ catb)
{
  int n = blockIdx.x, tid = threadIdx.x;
  __shared__ float qs[1024];
  __shared__ float vas[1024];
  __shared__ float es[512];
  __shared__ float red[8];
  for (int d=tid; d<1024; d+=256){ qs[d]=qbuf[n*1024+d]; vas[d]=bf2f(vaW[d]); }
  __syncthreads();
  int sl = seq_len[n];
  float vb = bf2f(vab[0]);
  for (int l=tid; l<512; l+=256) {
    const u16* up = Uah + ((size_t)n*512 + l)*1024;
    float a = 0.f;
    for (int d=0; d<1024; d+=8) {
      v8s uv = *(const v8s*)(up + d);
#pragma unroll
      for (int e=0;e<8;++e)
        a = fmaf(ftanh(bf2f((u16)uv[e]) + qs[d+e]), vas[d+e], a);
    }
    float ev = a + vb;
    if (l >= sl) ev += NEG_INF;
    es[l] = ev;
  }
  __syncthreads();
  float m = -3.4e38f;
  for (int l=tid; l<512; l+=256) m = fmaxf(m, es[l]);
#pragma unroll
  for (int off=1; off<64; off<<=1) m = fmaxf(m, __shfl_xor(m, off));
  if ((tid&63)==0) red[tid>>6] = m;
  __syncthreads();
  m = fmaxf(fmaxf(red[0],red[1]), fmaxf(red[2],red[3]));
  float s = 0.f;
  for (int l=tid; l<512; l+=256){ float p = __expf(es[l]-m); es[l]=p; s+=p; }
#pragma unroll
  for (int off=1; off<64; off<<=1) s += __shfl_xor(s, off);
  if ((tid&63)==0) red[4+(tid>>6)] = s;
  __syncthreads();
  float inv = 1.f/(red[4]+red[5]+red[6]+red[7]);
  int d0 = tid*4;
  float c0=0,c1=0,c2=0,c3=0;
  for (int l=0; l<512; ++l) {
    float a = es[l];
    const u16* hp = hid + ((size_t)n*512 + l)*1024 + d0;
    v4s hv = *(const v4s*)hp;
    c0 = fmaf(a, bf2f((u16)hv[0]), c0);
    c1 = fmaf(a, bf2f((u16)hv[1]), c1);
    c2 = fmaf(a, bf2f((u16)hv[2]), c2);
    c3 = fmaf(a, bf2f((u16)hv[3]), c3);
  }
  catb[n*2048 + d0 + 0] = f2bf(c0*inv);
  catb[n*2048 + d0 + 1] = f2bf(c1*inv);
  catb[n*2048 + d0 + 2] = f2bf(c2*inv);
  catb[n*2048 + d0 + 3] = f2bf(c3*inv);
}

__global__ void dec_pw(const float* __restrict__ g, u16* __restrict__ scat,
                       u16* __restrict__ catb, int it)
{
  int idx = blockIdx.x*256 + threadIdx.x;
  int n = idx >> 10, d = idx & 1023;
  float gi = g[(size_t)n*4096 + d];
  float gg = g[(size_t)n*4096 + 2048 + d];
  float go = g[(size_t)n*4096 + 3072 + d];
  float c = sigm(gi)*ftanh(gg);
  float s = sigm(go)*ftanh(c);
  u16 hb = f2bf(s);
  scat[((size_t)n*11 + it)*1024 + d] = hb;
  catb[n*2048 + 1024 + d] = hb;
}

__global__ void fill_sentinel(float* out, int nel){
  int i = blockIdx.x*256 + threadIdx.x;
  if (i < nel) out[i] = 12345.0f;
}

// ---------------------------------------------------------------------------
extern "C" void kernel_launch(void* const* d_in, const int* in_sizes, int n_in,
                              void* d_out, int out_size, void* d_ws, size_t ws_size,
                              hipStream_t stream)
{
  const int* X      = (const int*)d_in[0];
  const int* seqlen = (const int*)d_in[1];
  float* out = (float*)d_out;
  char* ws = (char*)d_ws;

  struct Seg { int idx; int n; };
  static const Seg segs[31] = {
    {2, 4096000},
    {3, 262144},{4,1048576},{5,2048},{6,2048},
    {7, 262144},{8,1048576},{9,2048},{10,2048},
    {11,2097152},{12,1048576},{13,2048},{14,2048},
    {15,2097152},{16,1048576},{17,2048},{18,2048},
    {19,1048576},{20,1024},
    {21,1048576},{22,1024},
    {23,1048576},{24,1024},
    {25,1024},{26,1},
    {27,4194304},{28,4194304},{29,4096},{30,4096},
    {31,10240000},{32,10000},
  };
  const u16* bp[33];
  CvtTab tab;
  size_t aoff = 0;
  for (int i = 0; i < 31; ++i) {
    bp[segs[i].idx] = (const u16*)(ws) + aoff;
    tab.src[i] = (const float*)d_in[segs[i].idx];
    tab.off[i] = (unsigned)aoff;
    tab.n[i]   = (unsigned)segs[i].n;
    aoff += (size_t)((segs[i].n + 7) & ~7);
  }
  tab.total = (unsigned)aoff;
  size_t arena_bytes = ((aoff*2 + 255) & ~(size_t)255);

  const size_t H0_OFF   = arena_bytes;
  const size_t HID_OFF  = H0_OFF   + 67108864;
  const size_t BAR_OFF  = HID_OFF  + 67108864;   // 16 KB progress words
  const size_t CATB_OFF = BAR_OFF  + 16384;
  const size_t QBUF_OFF = CATB_OFF + 262144;
  const size_t GDEC_OFF = QBUF_OFF + 262144;
  const size_t SCAT_OFF = GDEC_OFF + 1048576;
  const size_t NEED     = SCAT_OFF + 1441792;

  if (ws_size < NEED) {
    fill_sentinel<<<(out_size+255)/256, 256, 0, stream>>>(out, out_size);
    return;
  }

  u16*      h0   = (u16*)(ws + H0_OFF);
  u16*      Uah  = (u16*)(ws + H0_OFF);   // alias: h0 dead after encoder
  u16*      hid  = (u16*)(ws + HID_OFF);
  unsigned* bar  = (unsigned*)(ws + BAR_OFF);
  u16*      catb = (u16*)(ws + CATB_OFF);
  float*    qbuf = (float*)(ws + QBUF_OFF);
  float*    gdec = (float*)(ws + GDEC_OFF);
  u16*      scat = (u16*)(ws + SCAT_OFF);

  hipMemsetAsync(ws + BAR_OFF, 0, 16384, stream);

  {
    unsigned nth = (unsigned)(aoff / 8);
    cvt_all<<<(nth + 255)/256, 256, 0, stream>>>(tab, (u16*)ws);
  }

  // ---- encoder layer 0 (persistent scan) ----
  lstm_scan<0><<<128, 256, 0, stream>>>(
      bp[2], X, bp[3], bp[7], bp[4], bp[8],
      bp[5], bp[6], bp[9], bp[10], h0, bar);

  // ---- encoder layer 1 (separate progress region) ----
  lstm_scan<1><<<128, 256, 0, stream>>>(
      h0, nullptr, bp[11], bp[15], bp[12], bp[16],
      bp[13], bp[14], bp[17], bp[18], hid, bar + 1024);

  // ---- attention precompute ----
  gemm_bf16<<<dim3(256,8), 256, 0, stream>>>(hid, 1024, bp[23], bp[24], nullptr,
      Uah, 1024, 32768, 1024, 1024, GF_OUTBF16);
  gemm_bf16<<<dim3(1,8), 256, 0, stream>>>(hid, 524288, bp[19], bp[20], nullptr,
      catb + 1024, 2048, 64, 1024, 1024, GF_OUTBF16 | GF_TANH);

  // ---- 11 decoder steps ----
  for (int it = 0; it < 11; ++it) {
    gemm_bf16<<<dim3(1,8), 256, 0, stream>>>(catb + 1024, 2048, bp[21], bp[22], nullptr,
        qbuf, 1024, 64, 1024, 1024, 0);
    attn_step<<<64, 256, 0, stream>>>(qbuf, Uah, hid, seqlen, bp[25], bp[26], catb);
    gemm_bf16<<<dim3(1,32), 256, 0, stream>>>(catb, 2048, bp[27], bp[29], bp[30],
        gdec, 4096, 64, 4096, 1024, 0);
    gemm_bf16<<<dim3(1,32), 256, 0, stream>>>(catb + 1024, 2048, bp[28], nullptr, nullptr,
        gdec, 4096, 64, 4096, 1024, GF_ACCUM);
    dec_pw<<<256, 256, 0, stream>>>(gdec, scat, catb, it);
  }

  // ---- classifier (f32 output) ----
  gemm_bf16<<<dim3(6,79), 256, 0, stream>>>(scat, 1024, bp[31], bp[32], nullptr,
      out, 10000, 704, 10000, 1024, 0);
}